// Round 1
// baseline (2329.539 us; speedup 1.0000x reference)
//
#include <hip/hip_runtime.h>
#include <hip/hip_bf16.h>
#include <math.h>

#define HID 128

// ---------- fixed-degree mean/sum gather: out[i] = scale * sum_j x[src[i*k+j]] ----------
__global__ void k_gather_mean(const float* __restrict__ x,
                              const int* __restrict__ src,
                              int k, float scale,
                              float* __restrict__ out) {
  int i = blockIdx.x;
  int f = threadIdx.x;          // 0..127
  const int base = i * k;
  float s = 0.f;
  for (int j = 0; j < k; ++j) {
    int sj = src[base + j];
    s += x[sj * HID + f];
  }
  out[i * HID + f] = s * scale;
}

// ---------- fused GraphConv: xout = relu(agg@Wrel + x@Wroot + brel) ----------
// n divisible by ROWS for all layer sizes (20000/10000/5000).
template <int ROWS>
__global__ void k_conv(const float* __restrict__ agg, const float* __restrict__ x,
                       const float* __restrict__ Wrel, const float* __restrict__ Wroot,
                       const float* __restrict__ brel,
                       float* __restrict__ out) {
  int f  = threadIdx.x;         // 0..127 (output channel)
  int i0 = blockIdx.x * ROWS;
  float acc[ROWS];
  float b = brel[f];
#pragma unroll
  for (int r = 0; r < ROWS; ++r) acc[r] = b;
  for (int c = 0; c < HID; ++c) {
    float w1 = Wrel[c * HID + f];
    float w2 = Wroot[c * HID + f];
#pragma unroll
    for (int r = 0; r < ROWS; ++r) {
      int row = i0 + r;
      acc[r] += agg[row * HID + c] * w1 + x[row * HID + c] * w2;
    }
  }
#pragma unroll
  for (int r = 0; r < ROWS; ++r) {
    float v = acc[r];
    out[(i0 + r) * HID + f] = v > 0.f ? v : 0.f;
  }
}

// ---------- SAG score: score[i] = tanh( (sum_j x[src])·Wprel + x[i]·Wproot + bprel ) ----------
__global__ void k_score(const float* __restrict__ x, const int* __restrict__ src,
                        int k, const float* __restrict__ Wprel,
                        const float* __restrict__ Wproot, const float* __restrict__ bprel,
                        float* __restrict__ score, unsigned* __restrict__ key) {
  int i = blockIdx.x;
  int f = threadIdx.x;          // 0..127
  const int base = i * k;
  float snbr = 0.f;
  for (int j = 0; j < k; ++j) snbr += x[src[base + j] * HID + f];
  float acc = snbr * Wprel[f] + x[i * HID + f] * Wproot[f];
  for (int o = 32; o; o >>= 1) acc += __shfl_down(acc, o);
  __shared__ float red[2];
  if ((f & 63) == 0) red[f >> 6] = acc;
  __syncthreads();
  if (f == 0) {
    float s = tanhf(red[0] + red[1] + bprel[0]);
    score[i] = s;
    unsigned bb = __float_as_uint(s);
    key[i] = (bb & 0x80000000u) ? ~bb : (bb | 0x80000000u);  // monotone: bigger key == bigger score
  }
}

// ---------- single-block exact radix select: T = k-th largest key, G = #{key > T} ----------
__global__ void k_radix_select(const unsigned* __restrict__ key, int n, int k,
                               unsigned* __restrict__ outTG) {
  __shared__ unsigned hist[256];
  __shared__ unsigned sh_prefix, sh_remain;
  int tid = threadIdx.x, bs = blockDim.x;
  if (tid == 0) { sh_prefix = 0u; sh_remain = (unsigned)k; }
  __syncthreads();
  for (int pass = 0; pass < 4; ++pass) {
    int shift = 24 - pass * 8;
    for (int b = tid; b < 256; b += bs) hist[b] = 0u;
    __syncthreads();
    unsigned prefix = sh_prefix;
    unsigned himask = (pass == 0) ? 0u : (0xFFFFFFFFu << (shift + 8));
    for (int i = tid; i < n; i += bs) {
      unsigned kk = key[i];
      if ((kk & himask) == prefix)
        atomicAdd(&hist[(kk >> shift) & 255u], 1u);
    }
    __syncthreads();
    if (tid == 0) {
      unsigned remain = sh_remain;
      int b = 255;
      for (; b > 0; --b) {
        unsigned c = hist[b];
        if (remain > c) remain -= c; else break;
      }
      sh_prefix = prefix | ((unsigned)b << shift);
      sh_remain = remain;
    }
    __syncthreads();
  }
  if (tid == 0) { outTG[0] = sh_prefix; outTG[1] = (unsigned)k - sh_remain; }
}

// ---------- compaction: strictly greater (set deterministic, order not) ----------
__global__ void k_sel_gt(const unsigned* __restrict__ key, int n,
                         const unsigned* __restrict__ TG,
                         int* __restrict__ perm, int* __restrict__ cnt) {
  int i = blockIdx.x * blockDim.x + threadIdx.x;
  if (i >= n) return;
  if (key[i] > TG[0]) {
    int p = atomicAdd(cnt, 1);
    perm[p] = i;
  }
}

// ---------- boundary equals, index-ascending (deterministic tie-break like lax.top_k) ----------
__global__ void k_sel_eq(const unsigned* __restrict__ key, int n, int k,
                         const unsigned* __restrict__ TG, int* __restrict__ perm) {
  int lane = threadIdx.x;       // 64
  unsigned T = TG[0];
  int G = (int)TG[1];
  int need = k - G;
  int found = 0;
  for (int start = 0; start < n && found < need; start += 64) {
    int i = start + lane;
    bool eq = (i < n) && (key[i] == T);
    unsigned long long m = __ballot(eq);
    int before = __popcll(m & ((1ull << lane) - 1ull));
    if (eq && (found + before) < need) perm[G + found + before] = i;
    found += __popcll(m);
  }
}

// ---------- pooled gather: xout[j] = x[perm[j]] * score[perm[j]]; pos gather ----------
__global__ void k_pool(const float* __restrict__ x, const float* __restrict__ score,
                       const int* __restrict__ perm, const float* __restrict__ pos_in,
                       float* __restrict__ xout, float* __restrict__ pos_out, int do_pos) {
  int j = blockIdx.x;
  int f = threadIdx.x;          // 0..127
  int node = perm[j];
  float v = score[node];
  xout[j * HID + f] = x[node * HID + f] * v;
  if (do_pos && f < 2) pos_out[j * 2 + f] = pos_in[node * 2 + f];
}

// ---------- column max over m rows -> xs_out[128] ----------
__global__ void k_colmax(const float* __restrict__ x, int m, float* __restrict__ xs_out) {
  int f = blockIdx.x;           // column
  int tid = threadIdx.x;        // 256
  float mx = -1e30f;
  for (int j = tid; j < m; j += blockDim.x) mx = fmaxf(mx, x[j * HID + f]);
  for (int o = 32; o; o >>= 1) mx = fmaxf(mx, __shfl_down(mx, o));
  __shared__ float red[4];
  if ((tid & 63) == 0) red[tid >> 6] = mx;
  __syncthreads();
  if (tid == 0) xs_out[f] = fmaxf(fmaxf(red[0], red[1]), fmaxf(red[2], red[3]));
}

// ---------- brute-force KNN (2D), k nearest excluding self ----------
template <int K>
__global__ void k_knn(const float* __restrict__ pos, int m, int* __restrict__ src_out) {
  const int CH = 2048;
  __shared__ float2 cp[CH];
  int q = blockIdx.x * blockDim.x + threadIdx.x;
  float qx = 0.f, qy = 0.f;
  if (q < m) { qx = pos[q * 2]; qy = pos[q * 2 + 1]; }
  float bd[K]; int bi[K];
#pragma unroll
  for (int t = 0; t < K; ++t) { bd[t] = 1e30f; bi[t] = 0; }
  for (int start = 0; start < m; start += CH) {
    for (int c = threadIdx.x; c < CH; c += blockDim.x) {
      int g = start + c;
      float2 p;
      if (g < m) { p.x = pos[g * 2]; p.y = pos[g * 2 + 1]; }
      else       { p.x = 1e15f;      p.y = 1e15f; }
      cp[c] = p;
    }
    __syncthreads();
    int lim = min(CH, m - start);
    if (q < m) {
      for (int c = 0; c < lim; ++c) {
        float dx = qx - cp[c].x, dy = qy - cp[c].y;
        float d = dx * dx + dy * dy;
        int g = start + c;
        if (g == q) continue;                  // loop=False (diag = inf)
        if (d < bd[K - 1]) {
          float dd = d; int ii = g;
#pragma unroll
          for (int t = 0; t < K; ++t) {        // branchless sorted insert, static indices
            bool sw = dd < bd[t];
            float od = bd[t]; int oi = bi[t];
            if (sw) { bd[t] = dd; bi[t] = ii; dd = od; ii = oi; }
          }
        }
      }
    }
    __syncthreads();
  }
  if (q < m) {
#pragma unroll
    for (int t = 0; t < K; ++t) src_out[q * K + t] = bi[t];
  }
}

// ---------- final MLP head ----------
__global__ void k_final(const float* __restrict__ xs, const float* __restrict__ W1,
                        const float* __restrict__ b1, const float* __restrict__ W2,
                        const float* __restrict__ b2, float* __restrict__ out) {
  __shared__ float h1[HID];
  int f = threadIdx.x;          // 128
  float acc = b1[f];
  for (int c = 0; c < 3 * HID; ++c) acc += xs[c] * W1[c * HID + f];
  h1[f] = acc > 0.f ? acc : 0.f;
  __syncthreads();
  if (f < 5) {
    float a = b2[f];
    for (int c = 0; c < HID; ++c) a += h1[c] * W2[c * 5 + f];
    out[f] = a;
  }
}

extern "C" void kernel_launch(void* const* d_in, const int* in_sizes, int n_in,
                              void* d_out, int out_size, void* d_ws, size_t ws_size,
                              hipStream_t stream) {
  const float* x_in   = (const float*)d_in[0];
  const float* pos_in = (const float*)d_in[1];
  const int*   ei     = (const int*)d_in[2];
  const float* Wrel   = (const float*)d_in[3];
  const float* brel   = (const float*)d_in[4];
  const float* Wroot  = (const float*)d_in[5];
  const float* Wprel  = (const float*)d_in[6];
  const float* bprel  = (const float*)d_in[7];
  const float* Wproot = (const float*)d_in[8];
  const float* W1     = (const float*)d_in[9];
  const float* b1     = (const float*)d_in[10];
  const float* W2     = (const float*)d_in[11];
  const float* b2     = (const float*)d_in[12];
  float* out = (float*)d_out;

  const int N0 = in_sizes[0] / HID;   // 20000
  const int E0 = in_sizes[2] / 2;     // 120000
  const int k0 = E0 / N0;             // 6

  // workspace layout
  char* w = (char*)d_ws;
  float*    xB     = (float*)w;    w += (size_t)N0 * HID * 4;        // conv output (max N0 rows)
  float*    agg    = (float*)w;    w += (size_t)N0 * HID * 4;        // aggregation (max N0 rows)
  float*    xA     = (float*)w;    w += (size_t)(N0 / 2) * HID * 4;  // pooled x (max N0/2 rows)
  float*    score  = (float*)w;    w += (size_t)N0 * 4;
  unsigned* key    = (unsigned*)w; w += (size_t)N0 * 4;
  float*    posA   = (float*)w;    w += (size_t)(N0 / 2) * 2 * 4;
  float*    posB   = (float*)w;    w += (size_t)(N0 / 2) * 2 * 4;
  int*      srcbuf = (int*)w;      w += (size_t)(N0 / 2) * 8 * 4;    // max m*k = 10000*6 / 5000*8
  int*      permb  = (int*)w;      w += (size_t)(N0 / 2) * 4;
  float*    xs     = (float*)w;    w += 3 * HID * 4;
  unsigned* TG     = (unsigned*)w; w += 2 * 4;
  int*      cnt    = (int*)w;      w += 4 * 4;
  (void)ws_size; (void)n_in; (void)out_size;

  hipMemsetAsync(cnt, 0, 16, stream);

  int n = N0;
  const float* xcur   = x_in;
  const float* poscur = pos_in;
  const int*   srccur = ei;        // row 0 of edge_index = src
  int kcur = k0;

  for (int l = 0; l < 3; ++l) {
    const int kk = n / 2;
    k_gather_mean<<<n, HID, 0, stream>>>(xcur, srccur, kcur, 1.f / (float)kcur, agg);
    k_conv<8><<<n / 8, HID, 0, stream>>>(agg, xcur, Wrel + l * HID * HID,
                                         Wroot + l * HID * HID, brel + l * HID, xB);
    k_score<<<n, HID, 0, stream>>>(xB, srccur, kcur, Wprel + l * HID,
                                   Wproot + l * HID, bprel + l, score, key);
    k_radix_select<<<1, 1024, 0, stream>>>(key, n, kk, TG);
    k_sel_gt<<<(n + 255) / 256, 256, 0, stream>>>(key, n, TG, permb, cnt + l);
    k_sel_eq<<<1, 64, 0, stream>>>(key, n, kk, TG, permb);
    float* pos_out = (l == 0) ? posA : posB;
    k_pool<<<kk, HID, 0, stream>>>(xB, score, permb, poscur, xA, pos_out, l < 2 ? 1 : 0);
    k_colmax<<<HID, 256, 0, stream>>>(xA, kk, xs + l * HID);
    n = kk;
    if (l == 0)      { k_knn<6><<<(n + 127) / 128, 128, 0, stream>>>(posA, n, srcbuf); kcur = 6; }
    else if (l == 1) { k_knn<8><<<(n + 127) / 128, 128, 0, stream>>>(posB, n, srcbuf); kcur = 8; }
    // layer 2's KnnEdges output is never consumed -> skipped
    xcur = xA; poscur = pos_out; srccur = srcbuf;
  }
  k_final<<<1, HID, 0, stream>>>(xs, W1, b1, W2, b2, out);
}

// Round 2
// 785.609 us; speedup vs baseline: 2.9653x; 2.9653x over previous
//
#include <hip/hip_runtime.h>
#include <hip/hip_bf16.h>
#include <math.h>

#define HID 128

// ---------- fixed-degree mean/sum gather: out[i] = scale * sum_j x[src[i*k+j]] ----------
__global__ void k_gather_mean(const float* __restrict__ x,
                              const int* __restrict__ src,
                              int k, float scale,
                              float* __restrict__ out) {
  int i = blockIdx.x;
  int f = threadIdx.x;          // 0..127
  const int base = i * k;
  float s = 0.f;
  for (int j = 0; j < k; ++j) {
    int sj = src[base + j];
    s += x[sj * HID + f];
  }
  out[i * HID + f] = s * scale;
}

// ---------- fused GraphConv: xout = relu(agg@Wrel + x@Wroot + brel) ----------
template <int ROWS>
__global__ void k_conv(const float* __restrict__ agg, const float* __restrict__ x,
                       const float* __restrict__ Wrel, const float* __restrict__ Wroot,
                       const float* __restrict__ brel,
                       float* __restrict__ out) {
  int f  = threadIdx.x;         // 0..127 (output channel)
  int i0 = blockIdx.x * ROWS;
  float acc[ROWS];
  float b = brel[f];
#pragma unroll
  for (int r = 0; r < ROWS; ++r) acc[r] = b;
  for (int c = 0; c < HID; ++c) {
    float w1 = Wrel[c * HID + f];
    float w2 = Wroot[c * HID + f];
#pragma unroll
    for (int r = 0; r < ROWS; ++r) {
      int row = i0 + r;
      acc[r] += agg[row * HID + c] * w1 + x[row * HID + c] * w2;
    }
  }
#pragma unroll
  for (int r = 0; r < ROWS; ++r) {
    float v = acc[r];
    out[(i0 + r) * HID + f] = v > 0.f ? v : 0.f;
  }
}

// ---------- SAG score ----------
__global__ void k_score(const float* __restrict__ x, const int* __restrict__ src,
                        int k, const float* __restrict__ Wprel,
                        const float* __restrict__ Wproot, const float* __restrict__ bprel,
                        float* __restrict__ score, unsigned* __restrict__ key) {
  int i = blockIdx.x;
  int f = threadIdx.x;          // 0..127
  const int base = i * k;
  float snbr = 0.f;
  for (int j = 0; j < k; ++j) snbr += x[src[base + j] * HID + f];
  float acc = snbr * Wprel[f] + x[i * HID + f] * Wproot[f];
  for (int o = 32; o; o >>= 1) acc += __shfl_down(acc, o);
  __shared__ float red[2];
  if ((f & 63) == 0) red[f >> 6] = acc;
  __syncthreads();
  if (f == 0) {
    float s = tanhf(red[0] + red[1] + bprel[0]);
    score[i] = s;
    unsigned bb = __float_as_uint(s);
    key[i] = (bb & 0x80000000u) ? ~bb : (bb | 0x80000000u);
  }
}

// ---------- single-block exact radix select ----------
__global__ void k_radix_select(const unsigned* __restrict__ key, int n, int k,
                               unsigned* __restrict__ outTG) {
  __shared__ unsigned hist[256];
  __shared__ unsigned sh_prefix, sh_remain;
  int tid = threadIdx.x, bs = blockDim.x;
  if (tid == 0) { sh_prefix = 0u; sh_remain = (unsigned)k; }
  __syncthreads();
  for (int pass = 0; pass < 4; ++pass) {
    int shift = 24 - pass * 8;
    for (int b = tid; b < 256; b += bs) hist[b] = 0u;
    __syncthreads();
    unsigned prefix = sh_prefix;
    unsigned himask = (pass == 0) ? 0u : (0xFFFFFFFFu << (shift + 8));
    for (int i = tid; i < n; i += bs) {
      unsigned kk = key[i];
      if ((kk & himask) == prefix)
        atomicAdd(&hist[(kk >> shift) & 255u], 1u);
    }
    __syncthreads();
    if (tid == 0) {
      unsigned remain = sh_remain;
      int b = 255;
      for (; b > 0; --b) {
        unsigned c = hist[b];
        if (remain > c) remain -= c; else break;
      }
      sh_prefix = prefix | ((unsigned)b << shift);
      sh_remain = remain;
    }
    __syncthreads();
  }
  if (tid == 0) { outTG[0] = sh_prefix; outTG[1] = (unsigned)k - sh_remain; }
}

// ---------- compaction: strictly greater ----------
__global__ void k_sel_gt(const unsigned* __restrict__ key, int n,
                         const unsigned* __restrict__ TG,
                         int* __restrict__ perm, int* __restrict__ cnt) {
  int i = blockIdx.x * blockDim.x + threadIdx.x;
  if (i >= n) return;
  if (key[i] > TG[0]) {
    int p = atomicAdd(cnt, 1);
    perm[p] = i;
  }
}

// ---------- boundary equals, index-ascending ----------
__global__ void k_sel_eq(const unsigned* __restrict__ key, int n, int k,
                         const unsigned* __restrict__ TG, int* __restrict__ perm) {
  int lane = threadIdx.x;       // 64
  unsigned T = TG[0];
  int G = (int)TG[1];
  int need = k - G;
  int found = 0;
  for (int start = 0; start < n && found < need; start += 64) {
    int i = start + lane;
    bool eq = (i < n) && (key[i] == T);
    unsigned long long m = __ballot(eq);
    int before = __popcll(m & ((1ull << lane) - 1ull));
    if (eq && (found + before) < need) perm[G + found + before] = i;
    found += __popcll(m);
  }
}

// ---------- pooled gather ----------
__global__ void k_pool(const float* __restrict__ x, const float* __restrict__ score,
                       const int* __restrict__ perm, const float* __restrict__ pos_in,
                       float* __restrict__ xout, float* __restrict__ pos_out, int do_pos) {
  int j = blockIdx.x;
  int f = threadIdx.x;          // 0..127
  int node = perm[j];
  float v = score[node];
  xout[j * HID + f] = x[node * HID + f] * v;
  if (do_pos && f < 2) pos_out[j * 2 + f] = pos_in[node * 2 + f];
}

// ---------- column max ----------
__global__ void k_colmax(const float* __restrict__ x, int m, float* __restrict__ xs_out) {
  int f = blockIdx.x;
  int tid = threadIdx.x;        // 256
  float mx = -1e30f;
  for (int j = tid; j < m; j += blockDim.x) mx = fmaxf(mx, x[j * HID + f]);
  for (int o = 32; o; o >>= 1) mx = fmaxf(mx, __shfl_down(mx, o));
  __shared__ float red[4];
  if ((tid & 63) == 0) red[tid >> 6] = mx;
  __syncthreads();
  if (tid == 0) xs_out[f] = fmaxf(fmaxf(red[0], red[1]), fmaxf(red[2], red[3]));
}

// ---------- KNN: one wave per query; LDS-staged candidate chunks; wave-merge top-K ----------
template <int K>
__global__ void k_knn(const float* __restrict__ pos, int m, int* __restrict__ src_out) {
  const int CH = 1024;
  __shared__ float2 cp[CH];
  const float2* p2 = (const float2*)pos;
  int wid  = threadIdx.x >> 6;
  int lane = threadIdx.x & 63;
  int nw   = blockDim.x >> 6;
  int q = blockIdx.x * nw + wid;
  bool active = q < m;
  float qx = 0.f, qy = 0.f;
  if (active) { float2 qq = p2[q]; qx = qq.x; qy = qq.y; }

  float bd[K]; int bi[K];
#pragma unroll
  for (int t = 0; t < K; ++t) { bd[t] = 1e30f; bi[t] = 0; }

  for (int start = 0; start < m; start += CH) {
    int lim = min(CH, m - start);
    __syncthreads();
    for (int c = threadIdx.x; c < lim; c += blockDim.x) cp[c] = p2[start + c];
    __syncthreads();
    if (active) {
      for (int c = lane; c < lim; c += 64) {
        int g = start + c;
        float2 pp = cp[c];
        float dx = qx - pp.x, dy = qy - pp.y;
        float d = dx * dx + dy * dy;
        if (g == q) continue;                  // loop=False
        if (d < bd[K - 1]) {
          float dd = d; int ii = g;
#pragma unroll
          for (int t = 0; t < K; ++t) {        // branchless sorted insert, static idx
            bool sw = dd < bd[t];
            float od = bd[t]; int oi = bi[t];
            if (sw) { bd[t] = dd; bi[t] = ii; dd = od; ii = oi; }
          }
        }
      }
    }
  }

  if (!active) return;
  // pack (dist,idx) -> u64; wave-merge K smallest across 64 lanes.
  unsigned long long key[K];
#pragma unroll
  for (int t = 0; t < K; ++t)
    key[t] = ((unsigned long long)__float_as_uint(bd[t]) << 32) | (unsigned)bi[t];
#pragma unroll
  for (int t = 0; t < K; ++t) {
    unsigned long long h = key[0];
    unsigned long long mn = h;
#pragma unroll
    for (int o = 1; o < 64; o <<= 1) {
      unsigned long long other = __shfl_xor(mn, o, 64);
      if (other < mn) mn = other;
    }
    if (lane == 0) src_out[q * K + t] = (int)(unsigned)(mn & 0xffffffffu);
    if (h == mn) {                             // owner advances (unique: idx in low bits)
#pragma unroll
      for (int s = 0; s < K - 1; ++s) key[s] = key[s + 1];
      key[K - 1] = ~0ull;
    }
  }
}

// ---------- final MLP head ----------
__global__ void k_final(const float* __restrict__ xs, const float* __restrict__ W1,
                        const float* __restrict__ b1, const float* __restrict__ W2,
                        const float* __restrict__ b2, float* __restrict__ out) {
  __shared__ float h1[HID];
  int f = threadIdx.x;          // 128
  float acc = b1[f];
  for (int c = 0; c < 3 * HID; ++c) acc += xs[c] * W1[c * HID + f];
  h1[f] = acc > 0.f ? acc : 0.f;
  __syncthreads();
  if (f < 5) {
    float a = b2[f];
    for (int c = 0; c < HID; ++c) a += h1[c] * W2[c * 5 + f];
    out[f] = a;
  }
}

extern "C" void kernel_launch(void* const* d_in, const int* in_sizes, int n_in,
                              void* d_out, int out_size, void* d_ws, size_t ws_size,
                              hipStream_t stream) {
  const float* x_in   = (const float*)d_in[0];
  const float* pos_in = (const float*)d_in[1];
  const int*   ei     = (const int*)d_in[2];
  const float* Wrel   = (const float*)d_in[3];
  const float* brel   = (const float*)d_in[4];
  const float* Wroot  = (const float*)d_in[5];
  const float* Wprel  = (const float*)d_in[6];
  const float* bprel  = (const float*)d_in[7];
  const float* Wproot = (const float*)d_in[8];
  const float* W1     = (const float*)d_in[9];
  const float* b1     = (const float*)d_in[10];
  const float* W2     = (const float*)d_in[11];
  const float* b2     = (const float*)d_in[12];
  float* out = (float*)d_out;

  const int N0 = in_sizes[0] / HID;   // 20000
  const int E0 = in_sizes[2] / 2;     // 120000
  const int k0 = E0 / N0;             // 6

  // workspace layout
  char* w = (char*)d_ws;
  float*    xB     = (float*)w;    w += (size_t)N0 * HID * 4;
  float*    agg    = (float*)w;    w += (size_t)N0 * HID * 4;
  float*    xA     = (float*)w;    w += (size_t)(N0 / 2) * HID * 4;
  float*    score  = (float*)w;    w += (size_t)N0 * 4;
  unsigned* key    = (unsigned*)w; w += (size_t)N0 * 4;
  float*    posA   = (float*)w;    w += (size_t)(N0 / 2) * 2 * 4;
  float*    posB   = (float*)w;    w += (size_t)(N0 / 2) * 2 * 4;
  int*      srcbuf = (int*)w;      w += (size_t)(N0 / 2) * 8 * 4;
  int*      permb  = (int*)w;      w += (size_t)(N0 / 2) * 4;
  float*    xs     = (float*)w;    w += 3 * HID * 4;
  unsigned* TG     = (unsigned*)w; w += 2 * 4;
  int*      cnt    = (int*)w;      w += 4 * 4;
  (void)ws_size; (void)n_in; (void)out_size;

  hipMemsetAsync(cnt, 0, 16, stream);

  int n = N0;
  const float* xcur   = x_in;
  const float* poscur = pos_in;
  const int*   srccur = ei;
  int kcur = k0;

  for (int l = 0; l < 3; ++l) {
    const int kk = n / 2;
    k_gather_mean<<<n, HID, 0, stream>>>(xcur, srccur, kcur, 1.f / (float)kcur, agg);
    k_conv<8><<<n / 8, HID, 0, stream>>>(agg, xcur, Wrel + l * HID * HID,
                                         Wroot + l * HID * HID, brel + l * HID, xB);
    k_score<<<n, HID, 0, stream>>>(xB, srccur, kcur, Wprel + l * HID,
                                   Wproot + l * HID, bprel + l, score, key);
    k_radix_select<<<1, 1024, 0, stream>>>(key, n, kk, TG);
    k_sel_gt<<<(n + 255) / 256, 256, 0, stream>>>(key, n, TG, permb, cnt + l);
    k_sel_eq<<<1, 64, 0, stream>>>(key, n, kk, TG, permb);
    float* pos_out = (l == 0) ? posA : posB;
    k_pool<<<kk, HID, 0, stream>>>(xB, score, permb, poscur, xA, pos_out, l < 2 ? 1 : 0);
    k_colmax<<<HID, 256, 0, stream>>>(xA, kk, xs + l * HID);
    n = kk;
    if (l == 0)      { k_knn<6><<<(n + 3) / 4, 256, 0, stream>>>(posA, n, srcbuf); kcur = 6; }
    else if (l == 1) { k_knn<8><<<(n + 3) / 4, 256, 0, stream>>>(posB, n, srcbuf); kcur = 8; }
    // layer 2's KnnEdges output is never consumed -> skipped
    xcur = xA; poscur = pos_out; srccur = srcbuf;
  }
  k_final<<<1, HID, 0, stream>>>(xs, W1, b1, W2, b2, out);
}

// Round 3
// 556.264 us; speedup vs baseline: 4.1878x; 1.4123x over previous
//
#include <hip/hip_runtime.h>
#include <hip/hip_bf16.h>
#include <math.h>

#define HID 128
#define MAXEQ 8192

// ---------- fused mean-gather + GraphConv: out = relu(mean_j x[src] @ Wrel + x @ Wroot + b) ----------
template <int ROWS>
__global__ void k_conv_fused(const float* __restrict__ x, const int* __restrict__ src,
                             int k, float invk,
                             const float* __restrict__ Wrel, const float* __restrict__ Wroot,
                             const float* __restrict__ brel, float* __restrict__ out) {
  __shared__ float4 sagg4[ROWS][HID / 4];
  __shared__ float4 sx4[ROWS][HID / 4];
  float* sagg = (float*)sagg4;
  float* sx   = (float*)sx4;
  int f  = threadIdx.x;          // 0..127
  int i0 = blockIdx.x * ROWS;
  for (int r = 0; r < ROWS; ++r) {
    int row = i0 + r;
    float s = 0.f;
    int base = row * k;
    for (int j = 0; j < k; ++j) s += x[src[base + j] * HID + f];
    sagg[r * HID + f] = s * invk;
    sx[r * HID + f]   = x[row * HID + f];
  }
  __syncthreads();
  float acc[ROWS];
  float b = brel[f];
#pragma unroll
  for (int r = 0; r < ROWS; ++r) acc[r] = b;
  for (int cq = 0; cq < HID / 4; ++cq) {
    float w1u[4], w2u[4];
#pragma unroll
    for (int u = 0; u < 4; ++u) {
      w1u[u] = Wrel[(cq * 4 + u) * HID + f];
      w2u[u] = Wroot[(cq * 4 + u) * HID + f];
    }
#pragma unroll
    for (int r = 0; r < ROWS; ++r) {
      float4 a  = sagg4[r][cq];
      float4 xx = sx4[r][cq];
      acc[r] += a.x * w1u[0] + a.y * w1u[1] + a.z * w1u[2] + a.w * w1u[3]
              + xx.x * w2u[0] + xx.y * w2u[1] + xx.z * w2u[2] + xx.w * w2u[3];
    }
  }
#pragma unroll
  for (int r = 0; r < ROWS; ++r) {
    float v = acc[r];
    out[(i0 + r) * HID + f] = v > 0.f ? v : 0.f;
  }
}

// ---------- SAG score ----------
__global__ void k_score(const float* __restrict__ x, const int* __restrict__ src,
                        int k, const float* __restrict__ Wprel,
                        const float* __restrict__ Wproot, const float* __restrict__ bprel,
                        float* __restrict__ score, unsigned* __restrict__ key) {
  int i = blockIdx.x;
  int f = threadIdx.x;          // 0..127
  const int base = i * k;
  float snbr = 0.f;
  for (int j = 0; j < k; ++j) snbr += x[src[base + j] * HID + f];
  float acc = snbr * Wprel[f] + x[i * HID + f] * Wproot[f];
  for (int o = 32; o; o >>= 1) acc += __shfl_down(acc, o);
  __shared__ float red[2];
  if ((f & 63) == 0) red[f >> 6] = acc;
  __syncthreads();
  if (f == 0) {
    float s = tanhf(red[0] + red[1] + bprel[0]);
    score[i] = s;
    unsigned bb = __float_as_uint(s);
    key[i] = (bb & 0x80000000u) ? ~bb : (bb | 0x80000000u);
  }
}

// ---------- single-block exact radix select (uint4-vectorized scan) ----------
__global__ void k_radix_select(const unsigned* __restrict__ key, int n, int k,
                               unsigned* __restrict__ outTG) {
  __shared__ unsigned hist[256];
  __shared__ unsigned sh_prefix, sh_remain;
  int tid = threadIdx.x, bs = blockDim.x;
  const uint4* key4 = (const uint4*)key;
  int n4 = n >> 2;               // n divisible by 4 (20000/10000/5000)
  if (tid == 0) { sh_prefix = 0u; sh_remain = (unsigned)k; }
  __syncthreads();
  for (int pass = 0; pass < 4; ++pass) {
    int shift = 24 - pass * 8;
    for (int b = tid; b < 256; b += bs) hist[b] = 0u;
    __syncthreads();
    unsigned prefix = sh_prefix;
    unsigned himask = (pass == 0) ? 0u : (0xFFFFFFFFu << (shift + 8));
    for (int i = tid; i < n4; i += bs) {
      uint4 kv = key4[i];
      unsigned a0 = kv.x, a1 = kv.y, a2 = kv.z, a3 = kv.w;
      if ((a0 & himask) == prefix) atomicAdd(&hist[(a0 >> shift) & 255u], 1u);
      if ((a1 & himask) == prefix) atomicAdd(&hist[(a1 >> shift) & 255u], 1u);
      if ((a2 & himask) == prefix) atomicAdd(&hist[(a2 >> shift) & 255u], 1u);
      if ((a3 & himask) == prefix) atomicAdd(&hist[(a3 >> shift) & 255u], 1u);
    }
    __syncthreads();
    if (tid == 0) {
      unsigned remain = sh_remain;
      int b = 255;
      for (; b > 0; --b) {
        unsigned c = hist[b];
        if (remain > c) remain -= c; else break;
      }
      sh_prefix = prefix | ((unsigned)b << shift);
      sh_remain = remain;
    }
    __syncthreads();
  }
  if (tid == 0) { outTG[0] = sh_prefix; outTG[1] = (unsigned)k - sh_remain; }
}

// ---------- compaction: strictly greater + capture boundary-equals ----------
__global__ void k_sel(const unsigned* __restrict__ key, int n,
                      const unsigned* __restrict__ TG,
                      int* __restrict__ perm, int* __restrict__ cntGt,
                      int* __restrict__ eqbuf, int* __restrict__ cntEq) {
  int i = blockIdx.x * blockDim.x + threadIdx.x;
  if (i >= n) return;
  unsigned kk = key[i], T = TG[0];
  if (kk > T) {
    perm[atomicAdd(cntGt, 1)] = i;
  } else if (kk == T) {
    int p = atomicAdd(cntEq, 1);
    if (p < MAXEQ) eqbuf[p] = i;
  }
}

// ---------- pick `need` lowest indices among boundary-equals (lax.top_k tie-break) ----------
__global__ void k_sel_eq_fin(const unsigned* __restrict__ TG, const int* __restrict__ eqbuf,
                             const int* __restrict__ cntEq, int* __restrict__ perm, int kk) {
  int lane = threadIdx.x;        // 64
  int G = (int)TG[1];
  int need = kk - G;
  int cnt = *cntEq; if (cnt > MAXEQ) cnt = MAXEQ;
  int prev = -1;
  for (int t = 0; t < need; ++t) {
    int mymin = 0x7fffffff;
    for (int u = lane; u < cnt; u += 64) {
      int v = eqbuf[u];
      if (v > prev && v < mymin) mymin = v;
    }
    for (int o = 1; o < 64; o <<= 1) mymin = min(mymin, __shfl_xor(mymin, o, 64));
    if (lane == 0) perm[G + t] = mymin;
    prev = mymin;
  }
}

// ---------- pooled gather + fused partial column-max (coalesced) ----------
template <int R>
__global__ void k_pool_pmax(const float* __restrict__ x, const float* __restrict__ score,
                            const int* __restrict__ perm, const float* __restrict__ pos_in,
                            float* __restrict__ xout, float* __restrict__ pos_out, int do_pos,
                            float* __restrict__ pmax) {
  int f = threadIdx.x;           // 0..127
  int j0 = blockIdx.x * R;
  float mx = -1e30f;
#pragma unroll
  for (int rr = 0; rr < R; ++rr) {
    int j = j0 + rr;
    int node = perm[j];
    float v = score[node];
    float val = x[node * HID + f] * v;
    xout[j * HID + f] = val;
    mx = fmaxf(mx, val);
    if (do_pos && f < 2) pos_out[j * 2 + f] = pos_in[node * 2 + f];
  }
  pmax[blockIdx.x * HID + f] = mx;
}

// ---------- final column-max over P partial rows ----------
__global__ void k_colmax_fin(const float* __restrict__ pmax, int P, float* __restrict__ xs_out) {
  __shared__ float red[8][HID];
  int f = threadIdx.x & 127, ch = threadIdx.x >> 7;  // 1024 threads
  float mx = -1e30f;
  for (int p = ch; p < P; p += 8) mx = fmaxf(mx, pmax[p * HID + f]);
  red[ch][f] = mx;
  __syncthreads();
  if (ch == 0) {
    float m2 = red[0][f];
#pragma unroll
    for (int u = 1; u < 8; ++u) m2 = fmaxf(m2, red[u][f]);
    xs_out[f] = m2;
  }
}

// ---------- grid build ----------
__global__ void k_grid_count(const float2* __restrict__ pos, int m, int G, float inv_w,
                             int* __restrict__ counts) {
  int i = blockIdx.x * blockDim.x + threadIdx.x;
  if (i >= m) return;
  float2 p = pos[i];
  int cx = min(G - 1, max(0, (int)(p.x * inv_w)));
  int cy = min(G - 1, max(0, (int)(p.y * inv_w)));
  atomicAdd(&counts[cy * G + cx], 1);
}

__global__ void k_grid_scan(const int* __restrict__ counts, int* __restrict__ starts,
                            int* __restrict__ cursor, int cells) {
  __shared__ int sums[1024];
  int t = threadIdx.x;
  int c0[4];
  int base = t * 4;
  int s = 0;
#pragma unroll
  for (int u = 0; u < 4; ++u) {
    int idx = base + u;
    c0[u] = (idx < cells) ? counts[idx] : 0;
    s += c0[u];
  }
  sums[t] = s;
  __syncthreads();
  int val = s;
  for (int off = 1; off < 1024; off <<= 1) {
    int other = (t >= off) ? sums[t - off] : 0;
    __syncthreads();
    val += other;
    sums[t] = val;
    __syncthreads();
  }
  int excl = val - s;
#pragma unroll
  for (int u = 0; u < 4; ++u) {
    int idx = base + u;
    if (idx < cells) { starts[idx] = excl; cursor[idx] = excl; excl += c0[u]; }
  }
}

__global__ void k_grid_scatter(const float2* __restrict__ pos, int m, int G, float inv_w,
                               int* __restrict__ cursor, float2* __restrict__ spos,
                               int* __restrict__ sidx) {
  int i = blockIdx.x * blockDim.x + threadIdx.x;
  if (i >= m) return;
  float2 p = pos[i];
  int cx = min(G - 1, max(0, (int)(p.x * inv_w)));
  int cy = min(G - 1, max(0, (int)(p.y * inv_w)));
  int pp = atomicAdd(&cursor[cy * G + cx], 1);
  spos[pp] = p;
  sidx[pp] = i;
}

// ---------- exact KNN via grid ring expansion ----------
template <int K>
__device__ inline void scan_cell(int c, int j, float2 qp,
                                 const float2* __restrict__ spos, const int* __restrict__ sidx,
                                 const int* __restrict__ starts, const int* __restrict__ counts,
                                 float (&bd)[K], int (&bi)[K]) {
  int s = starts[c], e = s + counts[c];
  for (int p = s; p < e; ++p) {
    if (p == j) continue;                      // self (loop=False)
    float2 pp = spos[p];
    float dx = qp.x - pp.x, dy = qp.y - pp.y;
    float d = dx * dx + dy * dy;
    if (d < bd[K - 1]) {
      float dd = d; int ii = sidx[p];
#pragma unroll
      for (int t = 0; t < K; ++t) {            // branchless sorted insert, static idx
        bool sw = dd < bd[t];
        float od = bd[t]; int oi = bi[t];
        if (sw) { bd[t] = dd; bi[t] = ii; dd = od; ii = oi; }
      }
    }
  }
}

template <int K>
__global__ void k_knn_grid(const float2* __restrict__ spos, const int* __restrict__ sidx,
                           const int* __restrict__ starts, const int* __restrict__ counts,
                           int m, int G, float w, float inv_w, int* __restrict__ src_out) {
  int j = blockIdx.x * blockDim.x + threadIdx.x;   // scatter position (spatially sorted)
  if (j >= m) return;
  float2 qp = spos[j];
  int q = sidx[j];
  int cx = min(G - 1, max(0, (int)(qp.x * inv_w)));
  int cy = min(G - 1, max(0, (int)(qp.y * inv_w)));
  float bd[K]; int bi[K];
#pragma unroll
  for (int t = 0; t < K; ++t) { bd[t] = 1e30f; bi[t] = 0; }
  for (int r = 0; r < 2 * G; ++r) {
    int ylo = max(0, cy - r), yhi = min(G - 1, cy + r);
    for (int y = ylo; y <= yhi; ++y) {
      if (y == cy - r || y == cy + r) {
        int xlo = max(0, cx - r), xhi = min(G - 1, cx + r);
        for (int x = xlo; x <= xhi; ++x)
          scan_cell<K>(y * G + x, j, qp, spos, sidx, starts, counts, bd, bi);
      } else {
        int xa = cx - r, xb = cx + r;
        if (xa >= 0) scan_cell<K>(y * G + xa, j, qp, spos, sidx, starts, counts, bd, bi);
        if (xb < G)  scan_cell<K>(y * G + xb, j, qp, spos, sidx, starts, counts, bd, bi);
      }
    }
    // termination: min possible distance to any unscanned cell region
    float bnd = 1e30f;
    if (cx - r > 0)     bnd = fminf(bnd, qp.x - (float)(cx - r) * w);
    if (cx + r < G - 1) bnd = fminf(bnd, (float)(cx + r + 1) * w - qp.x);
    if (cy - r > 0)     bnd = fminf(bnd, qp.y - (float)(cy - r) * w);
    if (cy + r < G - 1) bnd = fminf(bnd, (float)(cy + r + 1) * w - qp.y);
    if (bnd > 1e29f) break;                    // grid exhausted
    float bb = fmaxf(bnd, 0.f) * 0.999f;       // conservative fp margin
    if (bd[K - 1] < bb * bb) break;            // bd[K-1]<inf implies K found
  }
#pragma unroll
  for (int t = 0; t < K; ++t) src_out[q * K + t] = bi[t];
}

// ---------- final MLP head ----------
__global__ void k_final(const float* __restrict__ xs, const float* __restrict__ W1,
                        const float* __restrict__ b1, const float* __restrict__ W2,
                        const float* __restrict__ b2, float* __restrict__ out) {
  __shared__ float h1[HID];
  int f = threadIdx.x;          // 128
  float acc = b1[f];
  for (int c = 0; c < 3 * HID; ++c) acc += xs[c] * W1[c * HID + f];
  h1[f] = acc > 0.f ? acc : 0.f;
  __syncthreads();
  if (f < 5) {
    float a = b2[f];
    for (int c = 0; c < HID; ++c) a += h1[c] * W2[c * 5 + f];
    out[f] = a;
  }
}

extern "C" void kernel_launch(void* const* d_in, const int* in_sizes, int n_in,
                              void* d_out, int out_size, void* d_ws, size_t ws_size,
                              hipStream_t stream) {
  const float* x_in   = (const float*)d_in[0];
  const float* pos_in = (const float*)d_in[1];
  const int*   ei     = (const int*)d_in[2];
  const float* Wrel   = (const float*)d_in[3];
  const float* brel   = (const float*)d_in[4];
  const float* Wroot  = (const float*)d_in[5];
  const float* Wprel  = (const float*)d_in[6];
  const float* bprel  = (const float*)d_in[7];
  const float* Wproot = (const float*)d_in[8];
  const float* W1     = (const float*)d_in[9];
  const float* b1     = (const float*)d_in[10];
  const float* W2     = (const float*)d_in[11];
  const float* b2     = (const float*)d_in[12];
  float* out = (float*)d_out;

  const int N0 = in_sizes[0] / HID;   // 20000
  const int E0 = in_sizes[2] / 2;     // 120000
  const int k0 = E0 / N0;             // 6

  // workspace layout (all regions 16B-aligned)
  char* w = (char*)d_ws;
  float*    xB     = (float*)w;    w += (size_t)N0 * HID * 4;
  float*    xA     = (float*)w;    w += (size_t)(N0 / 2) * HID * 4;
  float*    score  = (float*)w;    w += (size_t)N0 * 4;
  unsigned* key    = (unsigned*)w; w += (size_t)N0 * 4;
  float*    posA   = (float*)w;    w += (size_t)(N0 / 2) * 2 * 4;
  float*    posB   = (float*)w;    w += (size_t)(N0 / 2) * 2 * 4;
  int*      srcbuf = (int*)w;      w += (size_t)(N0 / 2) * 8 * 4;
  int*      permb  = (int*)w;      w += (size_t)(N0 / 2) * 4;
  float*    pmax   = (float*)w;    w += (size_t)(N0 / 8) * HID * 4;   // max kk/4 rows
  float*    xs     = (float*)w;    w += 3 * HID * 4;
  unsigned* TG     = (unsigned*)w; w += 16;
  int*      cnt    = (int*)w;      w += 32;                            // cntGt[3], cntEq[3]
  int*      eqbuf  = (int*)w;      w += MAXEQ * 4;
  int*      counts = (int*)w;      w += 4096 * 4;
  int*      starts = (int*)w;      w += 4096 * 4;
  int*      cursor = (int*)w;      w += 4096 * 4;
  float2*   spos   = (float2*)w;   w += (size_t)(N0 / 2) * 8;
  int*      sidx   = (int*)w;      w += (size_t)(N0 / 2) * 4;
  (void)ws_size; (void)n_in; (void)out_size;

  hipMemsetAsync(cnt, 0, 32, stream);

  int n = N0;
  const float* xcur   = x_in;
  const float* poscur = pos_in;
  const int*   srccur = ei;
  int kcur = k0;

  for (int l = 0; l < 3; ++l) {
    const int kk = n / 2;
    k_conv_fused<8><<<n / 8, HID, 0, stream>>>(xcur, srccur, kcur, 1.f / (float)kcur,
                                               Wrel + l * HID * HID, Wroot + l * HID * HID,
                                               brel + l * HID, xB);
    k_score<<<n, HID, 0, stream>>>(xB, srccur, kcur, Wprel + l * HID,
                                   Wproot + l * HID, bprel + l, score, key);
    k_radix_select<<<1, 1024, 0, stream>>>(key, n, kk, TG);
    k_sel<<<(n + 255) / 256, 256, 0, stream>>>(key, n, TG, permb, cnt + l, eqbuf, cnt + 3 + l);
    k_sel_eq_fin<<<1, 64, 0, stream>>>(TG, eqbuf, cnt + 3 + l, permb, kk);
    float* pos_out = (l == 0) ? posA : posB;
    k_pool_pmax<4><<<kk / 4, HID, 0, stream>>>(xB, score, permb, poscur, xA, pos_out,
                                               l < 2 ? 1 : 0, pmax);
    k_colmax_fin<<<1, 1024, 0, stream>>>(pmax, kk / 4, xs + l * HID);
    n = kk;
    if (l < 2) {
      // grid-based exact KNN rebuild
      int G = (int)ceilf(sqrtf((float)n / 2.5f));
      if (G > 64) G = 64;
      if (G < 1) G = 1;
      int cells = G * G;
      float cw = 100.f / (float)G;
      float inv_w = (float)G / 100.f;
      hipMemsetAsync(counts, 0, (size_t)cells * 4, stream);
      k_grid_count<<<(n + 255) / 256, 256, 0, stream>>>((const float2*)pos_out, n, G, inv_w, counts);
      k_grid_scan<<<1, 1024, 0, stream>>>(counts, starts, cursor, cells);
      k_grid_scatter<<<(n + 255) / 256, 256, 0, stream>>>((const float2*)pos_out, n, G, inv_w,
                                                          cursor, spos, sidx);
      if (l == 0) { k_knn_grid<6><<<(n + 255) / 256, 256, 0, stream>>>(spos, sidx, starts, counts,
                                                                      n, G, cw, inv_w, srcbuf); kcur = 6; }
      else        { k_knn_grid<8><<<(n + 255) / 256, 256, 0, stream>>>(spos, sidx, starts, counts,
                                                                      n, G, cw, inv_w, srcbuf); kcur = 8; }
    }
    // layer 2's KnnEdges output is never consumed -> skipped
    xcur = xA; poscur = pos_out; srccur = srcbuf;
  }
  k_final<<<1, HID, 0, stream>>>(xs, W1, b1, W2, b2, out);
}

// Round 4
// 494.269 us; speedup vs baseline: 4.7131x; 1.1254x over previous
//
#include <hip/hip_runtime.h>
#include <hip/hip_bf16.h>
#include <math.h>

#define HID 128
#define MAXEQ 8192

// ---------- fused mean-gather + GraphConv: out = relu(mean_j x[src] @ Wrel + x @ Wroot + b) ----------
template <int ROWS>
__global__ void k_conv_fused(const float* __restrict__ x, const int* __restrict__ src,
                             int k, float invk,
                             const float* __restrict__ Wrel, const float* __restrict__ Wroot,
                             const float* __restrict__ brel, float* __restrict__ out) {
  __shared__ float4 sagg4[ROWS][HID / 4];
  __shared__ float4 sx4[ROWS][HID / 4];
  float* sagg = (float*)sagg4;
  float* sx   = (float*)sx4;
  int f  = threadIdx.x;          // 0..127
  int i0 = blockIdx.x * ROWS;
  for (int r = 0; r < ROWS; ++r) {
    int row = i0 + r;
    float s = 0.f;
    int base = row * k;
    for (int j = 0; j < k; ++j) s += x[src[base + j] * HID + f];
    sagg[r * HID + f] = s * invk;
    sx[r * HID + f]   = x[row * HID + f];
  }
  __syncthreads();
  float acc[ROWS];
  float b = brel[f];
#pragma unroll
  for (int r = 0; r < ROWS; ++r) acc[r] = b;
  for (int cq = 0; cq < HID / 4; ++cq) {
    float w1u[4], w2u[4];
#pragma unroll
    for (int u = 0; u < 4; ++u) {
      w1u[u] = Wrel[(cq * 4 + u) * HID + f];
      w2u[u] = Wroot[(cq * 4 + u) * HID + f];
    }
#pragma unroll
    for (int r = 0; r < ROWS; ++r) {
      float4 a  = sagg4[r][cq];
      float4 xx = sx4[r][cq];
      acc[r] += a.x * w1u[0] + a.y * w1u[1] + a.z * w1u[2] + a.w * w1u[3]
              + xx.x * w2u[0] + xx.y * w2u[1] + xx.z * w2u[2] + xx.w * w2u[3];
    }
  }
#pragma unroll
  for (int r = 0; r < ROWS; ++r) {
    float v = acc[r];
    out[(i0 + r) * HID + f] = v > 0.f ? v : 0.f;
  }
}

// ---------- SAG score (numerics frozen — bit-matches reference selection) ----------
__global__ void k_score(const float* __restrict__ x, const int* __restrict__ src,
                        int k, const float* __restrict__ Wprel,
                        const float* __restrict__ Wproot, const float* __restrict__ bprel,
                        float* __restrict__ score, unsigned* __restrict__ key) {
  int i = blockIdx.x;
  int f = threadIdx.x;          // 0..127
  const int base = i * k;
  float snbr = 0.f;
  for (int j = 0; j < k; ++j) snbr += x[src[base + j] * HID + f];
  float acc = snbr * Wprel[f] + x[i * HID + f] * Wproot[f];
  for (int o = 32; o; o >>= 1) acc += __shfl_down(acc, o);
  __shared__ float red[2];
  if ((f & 63) == 0) red[f >> 6] = acc;
  __syncthreads();
  if (f == 0) {
    float s = tanhf(red[0] + red[1] + bprel[0]);
    score[i] = s;
    unsigned bb = __float_as_uint(s);
    key[i] = (bb & 0x80000000u) ? ~bb : (bb | 0x80000000u);
  }
}

// ---------- single-block exact radix select (uint4-vectorized scan) ----------
__global__ void k_radix_select(const unsigned* __restrict__ key, int n, int k,
                               unsigned* __restrict__ outTG) {
  __shared__ unsigned hist[256];
  __shared__ unsigned sh_prefix, sh_remain;
  int tid = threadIdx.x, bs = blockDim.x;
  const uint4* key4 = (const uint4*)key;
  int n4 = n >> 2;
  if (tid == 0) { sh_prefix = 0u; sh_remain = (unsigned)k; }
  __syncthreads();
  for (int pass = 0; pass < 4; ++pass) {
    int shift = 24 - pass * 8;
    for (int b = tid; b < 256; b += bs) hist[b] = 0u;
    __syncthreads();
    unsigned prefix = sh_prefix;
    unsigned himask = (pass == 0) ? 0u : (0xFFFFFFFFu << (shift + 8));
    for (int i = tid; i < n4; i += bs) {
      uint4 kv = key4[i];
      unsigned a0 = kv.x, a1 = kv.y, a2 = kv.z, a3 = kv.w;
      if ((a0 & himask) == prefix) atomicAdd(&hist[(a0 >> shift) & 255u], 1u);
      if ((a1 & himask) == prefix) atomicAdd(&hist[(a1 >> shift) & 255u], 1u);
      if ((a2 & himask) == prefix) atomicAdd(&hist[(a2 >> shift) & 255u], 1u);
      if ((a3 & himask) == prefix) atomicAdd(&hist[(a3 >> shift) & 255u], 1u);
    }
    __syncthreads();
    if (tid == 0) {
      unsigned remain = sh_remain;
      int b = 255;
      for (; b > 0; --b) {
        unsigned c = hist[b];
        if (remain > c) remain -= c; else break;
      }
      sh_prefix = prefix | ((unsigned)b << shift);
      sh_remain = remain;
    }
    __syncthreads();
  }
  if (tid == 0) { outTG[0] = sh_prefix; outTG[1] = (unsigned)k - sh_remain; }
}

// ---------- compaction: strictly greater + capture boundary-equals ----------
__global__ void k_sel(const unsigned* __restrict__ key, int n,
                      const unsigned* __restrict__ TG,
                      int* __restrict__ perm, int* __restrict__ cntGt,
                      int* __restrict__ eqbuf, int* __restrict__ cntEq) {
  int i = blockIdx.x * blockDim.x + threadIdx.x;
  if (i >= n) return;
  unsigned kk = key[i], T = TG[0];
  if (kk > T) {
    perm[atomicAdd(cntGt, 1)] = i;
  } else if (kk == T) {
    int p = atomicAdd(cntEq, 1);
    if (p < MAXEQ) eqbuf[p] = i;
  }
}

// ---------- pick `need` lowest indices among boundary-equals ----------
__global__ void k_sel_eq_fin(const unsigned* __restrict__ TG, const int* __restrict__ eqbuf,
                             const int* __restrict__ cntEq, int* __restrict__ perm, int kk) {
  int lane = threadIdx.x;        // 64
  int G = (int)TG[1];
  int need = kk - G;
  int cnt = *cntEq; if (cnt > MAXEQ) cnt = MAXEQ;
  int prev = -1;
  for (int t = 0; t < need; ++t) {
    int mymin = 0x7fffffff;
    for (int u = lane; u < cnt; u += 64) {
      int v = eqbuf[u];
      if (v > prev && v < mymin) mymin = v;
    }
    for (int o = 1; o < 64; o <<= 1) mymin = min(mymin, __shfl_xor(mymin, o, 64));
    if (lane == 0) perm[G + t] = mymin;
    prev = mymin;
  }
}

// ---------- pooled gather + fused global column-max via order-preserving atomicMax ----------
template <int R>
__global__ void k_pool_amax(const float* __restrict__ x, const float* __restrict__ score,
                            const int* __restrict__ perm, const float* __restrict__ pos_in,
                            float* __restrict__ xout, float* __restrict__ pos_out, int store,
                            unsigned* __restrict__ xsmax) {
  int f = threadIdx.x;           // 0..127
  int j0 = blockIdx.x * R;
  float mx = -1e30f;
#pragma unroll
  for (int rr = 0; rr < R; ++rr) {
    int j = j0 + rr;
    int node = perm[j];
    float v = score[node];
    float val = x[node * HID + f] * v;
    if (store) {
      xout[j * HID + f] = val;
      if (f < 2) pos_out[j * 2 + f] = pos_in[node * 2 + f];
    }
    mx = fmaxf(mx, val);
  }
  unsigned bb = __float_as_uint(mx);
  unsigned mkey = (bb & 0x80000000u) ? ~bb : (bb | 0x80000000u);
  atomicMax(&xsmax[f], mkey);
}

// ---------- grid build ----------
__global__ void k_grid_count(const float2* __restrict__ pos, int m, int G, float inv_w,
                             int* __restrict__ counts) {
  int i = blockIdx.x * blockDim.x + threadIdx.x;
  if (i >= m) return;
  float2 p = pos[i];
  int cx = min(G - 1, max(0, (int)(p.x * inv_w)));
  int cy = min(G - 1, max(0, (int)(p.y * inv_w)));
  atomicAdd(&counts[cy * G + cx], 1);
}

__global__ void k_grid_scan(const int* __restrict__ counts, int* __restrict__ starts,
                            int* __restrict__ cursor, int cells) {
  __shared__ int sums[1024];
  int t = threadIdx.x;
  int c0[4];
  int base = t * 4;
  int s = 0;
#pragma unroll
  for (int u = 0; u < 4; ++u) {
    int idx = base + u;
    c0[u] = (idx < cells) ? counts[idx] : 0;
    s += c0[u];
  }
  sums[t] = s;
  __syncthreads();
  int val = s;
  for (int off = 1; off < 1024; off <<= 1) {
    int other = (t >= off) ? sums[t - off] : 0;
    __syncthreads();
    val += other;
    sums[t] = val;
    __syncthreads();
  }
  int excl = val - s;
#pragma unroll
  for (int u = 0; u < 4; ++u) {
    int idx = base + u;
    if (idx < cells) { starts[idx] = excl; cursor[idx] = excl; excl += c0[u]; }
  }
}

__global__ void k_grid_scatter(const float2* __restrict__ pos, int m, int G, float inv_w,
                               int* __restrict__ cursor, float2* __restrict__ spos,
                               int* __restrict__ sidx) {
  int i = blockIdx.x * blockDim.x + threadIdx.x;
  if (i >= m) return;
  float2 p = pos[i];
  int cx = min(G - 1, max(0, (int)(p.x * inv_w)));
  int cy = min(G - 1, max(0, (int)(p.y * inv_w)));
  int pp = atomicAdd(&cursor[cy * G + cx], 1);
  spos[pp] = p;
  sidx[pp] = i;
}

// ---------- exact KNN, one wave per query; spans are row-contiguous after spatial sort ----------
template <int K>
__global__ __launch_bounds__(256) void k_knn_wave(const float2* __restrict__ spos,
                           const int* __restrict__ sidx,
                           const int* __restrict__ starts, const int* __restrict__ counts,
                           int m, int G, float w, float inv_w, int* __restrict__ src_out) {
  int lane = threadIdx.x & 63;
  int j = blockIdx.x * (blockDim.x >> 6) + (threadIdx.x >> 6);
  if (j >= m) return;                      // wave-uniform exit
  float2 qp = spos[j];
  int q = sidx[j];
  int cx = min(G - 1, max(0, (int)(qp.x * inv_w)));
  int cy = min(G - 1, max(0, (int)(qp.y * inv_w)));

  float bd[K]; int bi[K];
#pragma unroll
  for (int t = 0; t < K; ++t) { bd[t] = 1e30f; bi[t] = 0; }

  auto scan_span = [&](int s, int e) {
    for (int p = s + lane; p < e; p += 64) {
      if (p == j) continue;                // self (loop=False)
      float2 pp = spos[p];
      float dx = qp.x - pp.x, dy = qp.y - pp.y;
      float d = dx * dx + dy * dy;
      if (d < bd[K - 1]) {
        float dd = d; int ii = sidx[p];
#pragma unroll
        for (int t = 0; t < K; ++t) {      // branchless sorted insert, static idx
          bool sw = dd < bd[t];
          float od = bd[t]; int oi = bi[t];
          if (sw) { bd[t] = dd; bi[t] = ii; dd = od; ii = oi; }
        }
      }
    }
  };

  // phase 1: 3x3 neighborhood; each grid row is a contiguous point span
  {
    int xl = max(0, cx - 1), xh = min(G - 1, cx + 1);
    int y0 = max(0, cy - 1), y1 = min(G - 1, cy + 1);
    int ss[3], ee[3]; int nr = 0;
    for (int y = y0; y <= y1; ++y) {       // prefetch span bounds (independent loads)
      int b = y * G;
      ss[nr] = starts[b + xl];
      ee[nr] = starts[b + xh] + counts[b + xh];
      ++nr;
    }
    for (int t = 0; t < nr; ++t) scan_span(ss[t], ee[t]);
  }

  int r = 1;
  unsigned long long mg[K];
  while (true) {
    // non-destructive wave merge: global top-K + kth distance
    unsigned long long tmp[K];
#pragma unroll
    for (int t = 0; t < K; ++t)
      tmp[t] = ((unsigned long long)__float_as_uint(bd[t]) << 32) | (unsigned)bi[t];
#pragma unroll
    for (int t = 0; t < K; ++t) {
      unsigned long long mn = tmp[0];
#pragma unroll
      for (int o = 1; o < 64; o <<= 1) {
        unsigned long long ot = __shfl_xor(mn, o, 64);
        if (ot < mn) mn = ot;
      }
      mg[t] = mn;
      if (tmp[0] == mn) {
#pragma unroll
        for (int s2 = 0; s2 < K - 1; ++s2) tmp[s2] = tmp[s2 + 1];
        tmp[K - 1] = ~0ull;
      }
    }
    float kth = __uint_as_float((unsigned)(mg[K - 1] >> 32));
    // termination bound: distance to nearest unscanned region border
    float bnd = 1e30f;
    if (cx - r > 0)     bnd = fminf(bnd, qp.x - (float)(cx - r) * w);
    if (cx + r < G - 1) bnd = fminf(bnd, (float)(cx + r + 1) * w - qp.x);
    if (cy - r > 0)     bnd = fminf(bnd, qp.y - (float)(cy - r) * w);
    if (cy + r < G - 1) bnd = fminf(bnd, (float)(cy + r + 1) * w - qp.y);
    if (bnd > 1e29f) break;                // grid exhausted
    float bb = fmaxf(bnd, 0.f) * 0.999f;
    if (kth < bb * bb) break;              // NaN/huge kth -> false -> keep expanding
    ++r;
    // ring r: top/bottom rows are contiguous spans; middle rows two 1-cell spans
    int xl = max(0, cx - r), xh = min(G - 1, cx + r);
    int yt = cy - r, yb = cy + r;
    if (yt >= 0)     { int b = yt * G; scan_span(starts[b + xl], starts[b + xh] + counts[b + xh]); }
    if (yb <= G - 1) { int b = yb * G; scan_span(starts[b + xl], starts[b + xh] + counts[b + xh]); }
    int ylo = max(0, cy - r + 1), yhi = min(G - 1, cy + r - 1);
    for (int y = ylo; y <= yhi; ++y) {
      int b = y * G;
      if (cx - r >= 0)     { int c = b + cx - r; scan_span(starts[c], starts[c] + counts[c]); }
      if (cx + r <= G - 1) { int c = b + cx + r; scan_span(starts[c], starts[c] + counts[c]); }
    }
  }
  if (lane == 0) {
#pragma unroll
    for (int t = 0; t < K; ++t) src_out[q * K + t] = (int)(unsigned)(mg[t] & 0xffffffffu);
  }
}

// ---------- final MLP head (unmaps atomic column-max keys) ----------
__global__ void k_final(const unsigned* __restrict__ xsmax, const float* __restrict__ W1,
                        const float* __restrict__ b1, const float* __restrict__ W2,
                        const float* __restrict__ b2, float* __restrict__ out) {
  __shared__ float sxs[3 * HID];
  __shared__ float h1[HID];
  int f = threadIdx.x;          // 128
  for (int t = f; t < 3 * HID; t += HID) {
    unsigned u = xsmax[t];
    sxs[t] = (u & 0x80000000u) ? __uint_as_float(u ^ 0x80000000u) : __uint_as_float(~u);
  }
  __syncthreads();
  float acc = b1[f];
  for (int c = 0; c < 3 * HID; ++c) acc += sxs[c] * W1[c * HID + f];
  h1[f] = acc > 0.f ? acc : 0.f;
  __syncthreads();
  if (f < 5) {
    float a = b2[f];
    for (int c = 0; c < HID; ++c) a += h1[c] * W2[c * 5 + f];
    out[f] = a;
  }
}

extern "C" void kernel_launch(void* const* d_in, const int* in_sizes, int n_in,
                              void* d_out, int out_size, void* d_ws, size_t ws_size,
                              hipStream_t stream) {
  const float* x_in   = (const float*)d_in[0];
  const float* pos_in = (const float*)d_in[1];
  const int*   ei     = (const int*)d_in[2];
  const float* Wrel   = (const float*)d_in[3];
  const float* brel   = (const float*)d_in[4];
  const float* Wroot  = (const float*)d_in[5];
  const float* Wprel  = (const float*)d_in[6];
  const float* bprel  = (const float*)d_in[7];
  const float* Wproot = (const float*)d_in[8];
  const float* W1     = (const float*)d_in[9];
  const float* b1     = (const float*)d_in[10];
  const float* W2     = (const float*)d_in[11];
  const float* b2     = (const float*)d_in[12];
  float* out = (float*)d_out;

  const int N0 = in_sizes[0] / HID;   // 20000
  const int E0 = in_sizes[2] / 2;     // 120000
  const int k0 = E0 / N0;             // 6

  // workspace layout (16B-aligned regions)
  char* w = (char*)d_ws;
  float*    xB     = (float*)w;    w += (size_t)N0 * HID * 4;
  float*    xA     = (float*)w;    w += (size_t)(N0 / 2) * HID * 4;
  float*    score  = (float*)w;    w += (size_t)N0 * 4;
  unsigned* key    = (unsigned*)w; w += (size_t)N0 * 4;
  float*    posA   = (float*)w;    w += (size_t)(N0 / 2) * 2 * 4;
  float*    posB   = (float*)w;    w += (size_t)(N0 / 2) * 2 * 4;
  int*      srcbuf = (int*)w;      w += (size_t)(N0 / 2) * 8 * 4;
  int*      permb  = (int*)w;      w += (size_t)(N0 / 2) * 4;
  unsigned* TG     = (unsigned*)w; w += 16;
  int*      cnt    = (int*)w;      w += 32;                 // cntGt[3], cntEq[3]
  unsigned* xsmax  = (unsigned*)w; w += 3 * HID * 4;        // memset together with cnt
  int*      eqbuf  = (int*)w;      w += MAXEQ * 4;
  int*      counts = (int*)w;      w += 4096 * 4;
  int*      starts = (int*)w;      w += 4096 * 4;
  int*      cursor = (int*)w;      w += 4096 * 4;
  float2*   spos   = (float2*)w;   w += (size_t)(N0 / 2) * 8;
  int*      sidx   = (int*)w;      w += (size_t)(N0 / 2) * 4;
  (void)ws_size; (void)n_in; (void)out_size;

  hipMemsetAsync(cnt, 0, 32 + 3 * HID * 4, stream);   // cnt + xsmax (contiguous)

  int n = N0;
  const float* xcur   = x_in;
  const float* poscur = pos_in;
  const int*   srccur = ei;
  int kcur = k0;

  for (int l = 0; l < 3; ++l) {
    const int kk = n / 2;
    k_conv_fused<8><<<n / 8, HID, 0, stream>>>(xcur, srccur, kcur, 1.f / (float)kcur,
                                               Wrel + l * HID * HID, Wroot + l * HID * HID,
                                               brel + l * HID, xB);
    k_score<<<n, HID, 0, stream>>>(xB, srccur, kcur, Wprel + l * HID,
                                   Wproot + l * HID, bprel + l, score, key);
    k_radix_select<<<1, 1024, 0, stream>>>(key, n, kk, TG);
    k_sel<<<(n + 255) / 256, 256, 0, stream>>>(key, n, TG, permb, cnt + l, eqbuf, cnt + 3 + l);
    k_sel_eq_fin<<<1, 64, 0, stream>>>(TG, eqbuf, cnt + 3 + l, permb, kk);
    float* pos_out = (l == 0) ? posA : posB;
    k_pool_amax<4><<<kk / 4, HID, 0, stream>>>(xB, score, permb, poscur, xA, pos_out,
                                               l < 2 ? 1 : 0, xsmax + l * HID);
    n = kk;
    if (l < 2) {
      int G = (int)ceilf(sqrtf((float)n / 2.5f));
      if (G > 64) G = 64;
      if (G < 1) G = 1;
      int cells = G * G;
      float cw = 100.f / (float)G;
      float inv_w = (float)G / 100.f;
      hipMemsetAsync(counts, 0, (size_t)cells * 4, stream);
      k_grid_count<<<(n + 255) / 256, 256, 0, stream>>>((const float2*)pos_out, n, G, inv_w, counts);
      k_grid_scan<<<1, 1024, 0, stream>>>(counts, starts, cursor, cells);
      k_grid_scatter<<<(n + 255) / 256, 256, 0, stream>>>((const float2*)pos_out, n, G, inv_w,
                                                          cursor, spos, sidx);
      if (l == 0) { k_knn_wave<6><<<(n + 3) / 4, 256, 0, stream>>>(spos, sidx, starts, counts,
                                                                   n, G, cw, inv_w, srcbuf); kcur = 6; }
      else        { k_knn_wave<8><<<(n + 3) / 4, 256, 0, stream>>>(spos, sidx, starts, counts,
                                                                   n, G, cw, inv_w, srcbuf); kcur = 8; }
    }
    xcur = xA; poscur = pos_out; srccur = srcbuf;
  }
  k_final<<<1, HID, 0, stream>>>(xsmax, W1, b1, W2, b2, out);
}

// Round 5
// 417.037 us; speedup vs baseline: 5.5859x; 1.1852x over previous
//
#include <hip/hip_runtime.h>
#include <hip/hip_bf16.h>
#include <math.h>

#define HID 128
#define MAXEQ 8192
#define PR 20   // rows per pool block (divides 10000/5000/2500)

// ---------- fused mean-gather + GraphConv: out = relu(mean_j x[src] @ Wrel + x @ Wroot + b) ----------
template <int ROWS>
__global__ void k_conv_fused(const float* __restrict__ x, const int* __restrict__ src,
                             int k, float invk,
                             const float* __restrict__ Wrel, const float* __restrict__ Wroot,
                             const float* __restrict__ brel, float* __restrict__ out) {
  __shared__ float4 sagg4[ROWS][HID / 4];
  __shared__ float4 sx4[ROWS][HID / 4];
  float* sagg = (float*)sagg4;
  float* sx   = (float*)sx4;
  int f  = threadIdx.x;          // 0..127
  int i0 = blockIdx.x * ROWS;
  for (int r = 0; r < ROWS; ++r) {
    int row = i0 + r;
    float s = 0.f;
    int base = row * k;
    for (int j = 0; j < k; ++j) s += x[src[base + j] * HID + f];
    sagg[r * HID + f] = s * invk;
    sx[r * HID + f]   = x[row * HID + f];
  }
  __syncthreads();
  float acc[ROWS];
  float b = brel[f];
#pragma unroll
  for (int r = 0; r < ROWS; ++r) acc[r] = b;
  for (int cq = 0; cq < HID / 4; ++cq) {
    float w1u[4], w2u[4];
#pragma unroll
    for (int u = 0; u < 4; ++u) {
      w1u[u] = Wrel[(cq * 4 + u) * HID + f];
      w2u[u] = Wroot[(cq * 4 + u) * HID + f];
    }
#pragma unroll
    for (int r = 0; r < ROWS; ++r) {
      float4 a  = sagg4[r][cq];
      float4 xx = sx4[r][cq];
      acc[r] += a.x * w1u[0] + a.y * w1u[1] + a.z * w1u[2] + a.w * w1u[3]
              + xx.x * w2u[0] + xx.y * w2u[1] + xx.z * w2u[2] + xx.w * w2u[3];
    }
  }
#pragma unroll
  for (int r = 0; r < ROWS; ++r) {
    float v = acc[r];
    out[(i0 + r) * HID + f] = v > 0.f ? v : 0.f;
  }
}

// ---------- SAG score (numerics frozen — bit-matches reference selection) ----------
__global__ void k_score(const float* __restrict__ x, const int* __restrict__ src,
                        int k, const float* __restrict__ Wprel,
                        const float* __restrict__ Wproot, const float* __restrict__ bprel,
                        float* __restrict__ score, unsigned* __restrict__ key) {
  int i = blockIdx.x;
  int f = threadIdx.x;          // 0..127
  const int base = i * k;
  float snbr = 0.f;
  for (int j = 0; j < k; ++j) snbr += x[src[base + j] * HID + f];
  float acc = snbr * Wprel[f] + x[i * HID + f] * Wproot[f];
  for (int o = 32; o; o >>= 1) acc += __shfl_down(acc, o);
  __shared__ float red[2];
  if ((f & 63) == 0) red[f >> 6] = acc;
  __syncthreads();
  if (f == 0) {
    float s = tanhf(red[0] + red[1] + bprel[0]);
    score[i] = s;
    unsigned bb = __float_as_uint(s);
    key[i] = (bb & 0x80000000u) ? ~bb : (bb | 0x80000000u);
  }
}

// ---------- single-block exact radix select (uint4-vectorized scan) ----------
__global__ void k_radix_select(const unsigned* __restrict__ key, int n, int k,
                               unsigned* __restrict__ outTG) {
  __shared__ unsigned hist[256];
  __shared__ unsigned sh_prefix, sh_remain;
  int tid = threadIdx.x, bs = blockDim.x;
  const uint4* key4 = (const uint4*)key;
  int n4 = n >> 2;
  if (tid == 0) { sh_prefix = 0u; sh_remain = (unsigned)k; }
  __syncthreads();
  for (int pass = 0; pass < 4; ++pass) {
    int shift = 24 - pass * 8;
    for (int b = tid; b < 256; b += bs) hist[b] = 0u;
    __syncthreads();
    unsigned prefix = sh_prefix;
    unsigned himask = (pass == 0) ? 0u : (0xFFFFFFFFu << (shift + 8));
    for (int i = tid; i < n4; i += bs) {
      uint4 kv = key4[i];
      unsigned a0 = kv.x, a1 = kv.y, a2 = kv.z, a3 = kv.w;
      if ((a0 & himask) == prefix) atomicAdd(&hist[(a0 >> shift) & 255u], 1u);
      if ((a1 & himask) == prefix) atomicAdd(&hist[(a1 >> shift) & 255u], 1u);
      if ((a2 & himask) == prefix) atomicAdd(&hist[(a2 >> shift) & 255u], 1u);
      if ((a3 & himask) == prefix) atomicAdd(&hist[(a3 >> shift) & 255u], 1u);
    }
    __syncthreads();
    if (tid == 0) {
      unsigned remain = sh_remain;
      int b = 255;
      for (; b > 0; --b) {
        unsigned c = hist[b];
        if (remain > c) remain -= c; else break;
      }
      sh_prefix = prefix | ((unsigned)b << shift);
      sh_remain = remain;
    }
    __syncthreads();
  }
  if (tid == 0) { outTG[0] = sh_prefix; outTG[1] = (unsigned)k - sh_remain; }
}

// ---------- compaction: strictly greater + capture boundary-equals ----------
__global__ void k_sel(const unsigned* __restrict__ key, int n,
                      const unsigned* __restrict__ TG,
                      int* __restrict__ perm, int* __restrict__ cntGt,
                      int* __restrict__ eqbuf, int* __restrict__ cntEq) {
  int i = blockIdx.x * blockDim.x + threadIdx.x;
  if (i >= n) return;
  unsigned kk = key[i], T = TG[0];
  if (kk > T) {
    perm[atomicAdd(cntGt, 1)] = i;
  } else if (kk == T) {
    int p = atomicAdd(cntEq, 1);
    if (p < MAXEQ) eqbuf[p] = i;
  }
}

// ---------- pick `need` lowest indices among boundary-equals ----------
__global__ void k_sel_eq_fin(const unsigned* __restrict__ TG, const int* __restrict__ eqbuf,
                             const int* __restrict__ cntEq, int* __restrict__ perm, int kk) {
  int lane = threadIdx.x;        // 64
  int G = (int)TG[1];
  int need = kk - G;
  int cnt = *cntEq; if (cnt > MAXEQ) cnt = MAXEQ;
  int prev = -1;
  for (int t = 0; t < need; ++t) {
    int mymin = 0x7fffffff;
    for (int u = lane; u < cnt; u += 64) {
      int v = eqbuf[u];
      if (v > prev && v < mymin) mymin = v;
    }
    for (int o = 1; o < 64; o <<= 1) mymin = min(mymin, __shfl_xor(mymin, o, 64));
    if (lane == 0) perm[G + t] = mymin;
    prev = mymin;
  }
}

// ---------- pooled gather + per-block column-max + fused grid-cell count ----------
template <int R>
__global__ __launch_bounds__(256) void k_pool_pmax(
    const float* __restrict__ x, const float* __restrict__ score,
    const int* __restrict__ perm, const float* __restrict__ pos_in,
    float* __restrict__ xout, float* __restrict__ pos_out, int store,
    float* __restrict__ pmax, int* __restrict__ counts, int G, float inv_w) {
  __shared__ float sm[2][HID];
  int f = threadIdx.x & 127;
  int half = threadIdx.x >> 7;
  int j0 = blockIdx.x * R;
  float mx = -1e30f;
  for (int r = half; r < R; r += 2) {
    int j = j0 + r;
    int node = perm[j];
    float v = score[node];
    float val = x[node * HID + f] * v;
    if (store) xout[j * HID + f] = val;
    mx = fmaxf(mx, val);
    if (store && f == 0) {
      float px = pos_in[node * 2], py = pos_in[node * 2 + 1];
      pos_out[j * 2] = px; pos_out[j * 2 + 1] = py;
      int cx = min(G - 1, max(0, (int)(px * inv_w)));
      int cy = min(G - 1, max(0, (int)(py * inv_w)));
      atomicAdd(&counts[cy * G + cx], 1);
    }
  }
  sm[half][f] = mx;
  __syncthreads();
  if (half == 0) pmax[blockIdx.x * HID + f] = fmaxf(sm[0][f], sm[1][f]);
}

// ---------- grid scan ----------
__global__ void k_grid_scan(const int* __restrict__ counts, int* __restrict__ starts,
                            int* __restrict__ cursor, int cells) {
  __shared__ int sums[1024];
  int t = threadIdx.x;
  int c0[4];
  int base = t * 4;
  int s = 0;
#pragma unroll
  for (int u = 0; u < 4; ++u) {
    int idx = base + u;
    c0[u] = (idx < cells) ? counts[idx] : 0;
    s += c0[u];
  }
  sums[t] = s;
  __syncthreads();
  int val = s;
  for (int off = 1; off < 1024; off <<= 1) {
    int other = (t >= off) ? sums[t - off] : 0;
    __syncthreads();
    val += other;
    sums[t] = val;
    __syncthreads();
  }
  int excl = val - s;
#pragma unroll
  for (int u = 0; u < 4; ++u) {
    int idx = base + u;
    if (idx < cells) { starts[idx] = excl; cursor[idx] = excl; excl += c0[u]; }
  }
}

__global__ void k_grid_scatter(const float2* __restrict__ pos, int m, int G, float inv_w,
                               int* __restrict__ cursor, float2* __restrict__ spos,
                               int* __restrict__ sidx) {
  int i = blockIdx.x * blockDim.x + threadIdx.x;
  if (i >= m) return;
  float2 p = pos[i];
  int cx = min(G - 1, max(0, (int)(p.x * inv_w)));
  int cy = min(G - 1, max(0, (int)(p.y * inv_w)));
  int pp = atomicAdd(&cursor[cy * G + cx], 1);
  spos[pp] = p;
  sidx[pp] = i;
}

// ---------- exact KNN, one wave per query; spans are row-contiguous after spatial sort ----------
template <int K>
__global__ __launch_bounds__(256) void k_knn_wave(const float2* __restrict__ spos,
                           const int* __restrict__ sidx,
                           const int* __restrict__ starts, const int* __restrict__ counts,
                           int m, int G, float w, float inv_w, int* __restrict__ src_out) {
  int lane = threadIdx.x & 63;
  int j = blockIdx.x * (blockDim.x >> 6) + (threadIdx.x >> 6);
  if (j >= m) return;                      // wave-uniform exit
  float2 qp = spos[j];
  int q = sidx[j];
  int cx = min(G - 1, max(0, (int)(qp.x * inv_w)));
  int cy = min(G - 1, max(0, (int)(qp.y * inv_w)));

  float bd[K]; int bi[K];
#pragma unroll
  for (int t = 0; t < K; ++t) { bd[t] = 1e30f; bi[t] = 0; }

  auto scan_span = [&](int s, int e) {
    for (int p = s + lane; p < e; p += 64) {
      if (p == j) continue;                // self (loop=False)
      float2 pp = spos[p];
      float dx = qp.x - pp.x, dy = qp.y - pp.y;
      float d = dx * dx + dy * dy;
      if (d < bd[K - 1]) {
        float dd = d; int ii = sidx[p];
#pragma unroll
        for (int t = 0; t < K; ++t) {      // branchless sorted insert, static idx
          bool sw = dd < bd[t];
          float od = bd[t]; int oi = bi[t];
          if (sw) { bd[t] = dd; bi[t] = ii; dd = od; ii = oi; }
        }
      }
    }
  };

  // phase 1: 3x3 neighborhood; each grid row is a contiguous point span
  {
    int xl = max(0, cx - 1), xh = min(G - 1, cx + 1);
    int y0 = max(0, cy - 1), y1 = min(G - 1, cy + 1);
    int ss[3], ee[3]; int nr = 0;
    for (int y = y0; y <= y1; ++y) {
      int b = y * G;
      ss[nr] = starts[b + xl];
      ee[nr] = starts[b + xh] + counts[b + xh];
      ++nr;
    }
    for (int t = 0; t < nr; ++t) scan_span(ss[t], ee[t]);
  }

  int r = 1;
  unsigned long long mg[K];
  while (true) {
    unsigned long long tmp[K];
#pragma unroll
    for (int t = 0; t < K; ++t)
      tmp[t] = ((unsigned long long)__float_as_uint(bd[t]) << 32) | (unsigned)bi[t];
#pragma unroll
    for (int t = 0; t < K; ++t) {
      unsigned long long mn = tmp[0];
#pragma unroll
      for (int o = 1; o < 64; o <<= 1) {
        unsigned long long ot = __shfl_xor(mn, o, 64);
        if (ot < mn) mn = ot;
      }
      mg[t] = mn;
      if (tmp[0] == mn) {
#pragma unroll
        for (int s2 = 0; s2 < K - 1; ++s2) tmp[s2] = tmp[s2 + 1];
        tmp[K - 1] = ~0ull;
      }
    }
    float kth = __uint_as_float((unsigned)(mg[K - 1] >> 32));
    float bnd = 1e30f;
    if (cx - r > 0)     bnd = fminf(bnd, qp.x - (float)(cx - r) * w);
    if (cx + r < G - 1) bnd = fminf(bnd, (float)(cx + r + 1) * w - qp.x);
    if (cy - r > 0)     bnd = fminf(bnd, qp.y - (float)(cy - r) * w);
    if (cy + r < G - 1) bnd = fminf(bnd, (float)(cy + r + 1) * w - qp.y);
    if (bnd > 1e29f) break;                // grid exhausted
    float bb = fmaxf(bnd, 0.f) * 0.999f;
    if (kth < bb * bb) break;
    ++r;
    int xl = max(0, cx - r), xh = min(G - 1, cx + r);
    int yt = cy - r, yb = cy + r;
    if (yt >= 0)     { int b = yt * G; scan_span(starts[b + xl], starts[b + xh] + counts[b + xh]); }
    if (yb <= G - 1) { int b = yb * G; scan_span(starts[b + xl], starts[b + xh] + counts[b + xh]); }
    int ylo = max(0, cy - r + 1), yhi = min(G - 1, cy + r - 1);
    for (int y = ylo; y <= yhi; ++y) {
      int b = y * G;
      if (cx - r >= 0)     { int c = b + cx - r; scan_span(starts[c], starts[c] + counts[c]); }
      if (cx + r <= G - 1) { int c = b + cx + r; scan_span(starts[c], starts[c] + counts[c]); }
    }
  }
  if (lane == 0) {
#pragma unroll
    for (int t = 0; t < K; ++t) src_out[q * K + t] = (int)(unsigned)(mg[t] & 0xffffffffu);
  }
}

// ---------- final: reduce pmax segments -> xs, then MLP head ----------
__global__ __launch_bounds__(1024) void k_final(const float* __restrict__ pmax,
                        int P0, int P1, int P2,
                        const float* __restrict__ W1, const float* __restrict__ b1,
                        const float* __restrict__ W2, const float* __restrict__ b2,
                        float* __restrict__ out) {
  __shared__ float red[8][HID];
  __shared__ float sxs[3 * HID];
  __shared__ float h1[HID];
  int f = threadIdx.x & 127, ch = threadIdx.x >> 7;   // 1024 threads
  int off0 = 0, off1 = P0, off2 = P0 + P1, off3 = P0 + P1 + P2;
  int lo[3] = {off0, off1, off2};
  int hi[3] = {off1, off2, off3};
  for (int l = 0; l < 3; ++l) {
    float mx = -1e30f;
    for (int p = lo[l] + ch; p < hi[l]; p += 8) mx = fmaxf(mx, pmax[p * HID + f]);
    red[ch][f] = mx;
    __syncthreads();
    if (ch == 0) {
      float m2 = red[0][f];
#pragma unroll
      for (int u = 1; u < 8; ++u) m2 = fmaxf(m2, red[u][f]);
      sxs[l * HID + f] = m2;
    }
    __syncthreads();
  }
  if (threadIdx.x < HID) {
    float acc = b1[f];
    for (int c = 0; c < 3 * HID; ++c) acc += sxs[c] * W1[c * HID + f];
    h1[f] = acc > 0.f ? acc : 0.f;
  }
  __syncthreads();
  if (threadIdx.x < 5) {
    float a = b2[threadIdx.x];
    for (int c = 0; c < HID; ++c) a += h1[c] * W2[c * 5 + threadIdx.x];
    out[threadIdx.x] = a;
  }
}

extern "C" void kernel_launch(void* const* d_in, const int* in_sizes, int n_in,
                              void* d_out, int out_size, void* d_ws, size_t ws_size,
                              hipStream_t stream) {
  const float* x_in   = (const float*)d_in[0];
  const float* pos_in = (const float*)d_in[1];
  const int*   ei     = (const int*)d_in[2];
  const float* Wrel   = (const float*)d_in[3];
  const float* brel   = (const float*)d_in[4];
  const float* Wroot  = (const float*)d_in[5];
  const float* Wprel  = (const float*)d_in[6];
  const float* bprel  = (const float*)d_in[7];
  const float* Wproot = (const float*)d_in[8];
  const float* W1     = (const float*)d_in[9];
  const float* b1     = (const float*)d_in[10];
  const float* W2     = (const float*)d_in[11];
  const float* b2     = (const float*)d_in[12];
  float* out = (float*)d_out;

  const int N0 = in_sizes[0] / HID;   // 20000
  const int E0 = in_sizes[2] / 2;     // 120000
  const int k0 = E0 / N0;             // 6
  const int P0 = (N0 / 2) / PR, P1 = (N0 / 4) / PR, P2 = (N0 / 8) / PR;  // 500/250/125

  // workspace layout (16B-aligned regions)
  char* w = (char*)d_ws;
  float*    xB     = (float*)w;    w += (size_t)N0 * HID * 4;
  float*    xA     = (float*)w;    w += (size_t)(N0 / 2) * HID * 4;
  float*    score  = (float*)w;    w += (size_t)N0 * 4;
  unsigned* key    = (unsigned*)w; w += (size_t)N0 * 4;
  float*    posA   = (float*)w;    w += (size_t)(N0 / 2) * 2 * 4;
  float*    posB   = (float*)w;    w += (size_t)(N0 / 2) * 2 * 4;
  int*      srcbuf = (int*)w;      w += (size_t)(N0 / 2) * 8 * 4;
  int*      permb  = (int*)w;      w += (size_t)(N0 / 2) * 4;
  float*    pmax   = (float*)w;    w += (size_t)(P0 + P1 + P2) * HID * 4;
  unsigned* TG     = (unsigned*)w; w += 16;
  int*      cnt    = (int*)w;      w += 32;                 // cntGt[3], cntEq[3]
  int*      eqbuf  = (int*)w;      w += MAXEQ * 4;
  int*      counts = (int*)w;      w += 4096 * 4;
  int*      starts = (int*)w;      w += 4096 * 4;
  int*      cursor = (int*)w;      w += 4096 * 4;
  float2*   spos   = (float2*)w;   w += (size_t)(N0 / 2) * 8;
  int*      sidx   = (int*)w;      w += (size_t)(N0 / 2) * 4;
  (void)ws_size; (void)n_in; (void)out_size;

  hipMemsetAsync(cnt, 0, 32, stream);

  int n = N0;
  const float* xcur   = x_in;
  const float* poscur = pos_in;
  const int*   srccur = ei;
  int kcur = k0;
  int Poff = 0;

  for (int l = 0; l < 3; ++l) {
    const int kk = n / 2;
    // grid geometry for the POOLED node set (kk nodes)
    int G = (int)ceilf(sqrtf((float)kk / 2.5f));
    if (G > 64) G = 64;
    if (G < 1) G = 1;
    int cells = G * G;
    float cw = 100.f / (float)G;
    float inv_w = (float)G / 100.f;

    k_conv_fused<8><<<n / 8, HID, 0, stream>>>(xcur, srccur, kcur, 1.f / (float)kcur,
                                               Wrel + l * HID * HID, Wroot + l * HID * HID,
                                               brel + l * HID, xB);
    k_score<<<n, HID, 0, stream>>>(xB, srccur, kcur, Wprel + l * HID,
                                   Wproot + l * HID, bprel + l, score, key);
    k_radix_select<<<1, 1024, 0, stream>>>(key, n, kk, TG);
    k_sel<<<(n + 255) / 256, 256, 0, stream>>>(key, n, TG, permb, cnt + l, eqbuf, cnt + 3 + l);
    k_sel_eq_fin<<<1, 64, 0, stream>>>(TG, eqbuf, cnt + 3 + l, permb, kk);

    float* pos_out = (l == 0) ? posA : posB;
    int store = (l < 2) ? 1 : 0;
    if (store) hipMemsetAsync(counts, 0, (size_t)cells * 4, stream);
    k_pool_pmax<PR><<<kk / PR, 256, 0, stream>>>(xB, score, permb, poscur, xA, pos_out,
                                                 store, pmax + (size_t)Poff * HID,
                                                 counts, G, inv_w);
    Poff += kk / PR;
    n = kk;
    if (l < 2) {
      k_grid_scan<<<1, 1024, 0, stream>>>(counts, starts, cursor, cells);
      k_grid_scatter<<<(n + 255) / 256, 256, 0, stream>>>((const float2*)pos_out, n, G, inv_w,
                                                          cursor, spos, sidx);
      if (l == 0) { k_knn_wave<6><<<(n + 3) / 4, 256, 0, stream>>>(spos, sidx, starts, counts,
                                                                   n, G, cw, inv_w, srcbuf); kcur = 6; }
      else        { k_knn_wave<8><<<(n + 3) / 4, 256, 0, stream>>>(spos, sidx, starts, counts,
                                                                   n, G, cw, inv_w, srcbuf); kcur = 8; }
    }
    xcur = xA; poscur = pos_out; srccur = srcbuf;
  }
  k_final<<<1, 1024, 0, stream>>>(pmax, P0, P1, P2, W1, b1, W2, b2, out);
}

// Round 6
// 380.706 us; speedup vs baseline: 6.1190x; 1.0954x over previous
//
#include <hip/hip_runtime.h>
#include <hip/hip_bf16.h>
#include <math.h>

#define HID 128
#define MAXEQ 8192
#define PR 20   // rows per pool block (divides 10000/5000/2500)

// ---------- fused mean-gather + GraphConv + score-scalar epilogue ----------
// out = relu(mean_j x[src] @ Wrel + x @ Wroot + b);  u = out·wprel, v = out·wproot
template <int ROWS, int K>
__global__ __launch_bounds__(128) void k_conv_fused(
    const float* __restrict__ x, const int* __restrict__ src, float invk,
    const float* __restrict__ Wrel, const float* __restrict__ Wroot,
    const float* __restrict__ brel,
    const float* __restrict__ wprel, const float* __restrict__ wproot,
    float* __restrict__ out, float* __restrict__ uo, float* __restrict__ vo) {
  __shared__ float4 sagg4[ROWS][HID / 4];
  __shared__ float4 sx4[ROWS][HID / 4];
  __shared__ int    ssrc[ROWS * K];
  __shared__ float  suv[2][2][ROWS];
  float* sagg = (float*)sagg4;
  float* sx   = (float*)sx4;
  int f  = threadIdx.x;          // 0..127
  int i0 = blockIdx.x * ROWS;
  if (f < ROWS * K) ssrc[f] = src[i0 * K + f];
  __syncthreads();
#pragma unroll
  for (int r = 0; r < ROWS; ++r) {
    float s = 0.f;
#pragma unroll
    for (int j = 0; j < K; ++j) s += x[(size_t)ssrc[r * K + j] * HID + f];
    sagg[r * HID + f] = s * invk;
    sx[r * HID + f]   = x[(size_t)(i0 + r) * HID + f];
  }
  __syncthreads();
  float acc[ROWS];
  float b = brel[f];
  float wpl = wprel[f], wpr = wproot[f];
#pragma unroll
  for (int r = 0; r < ROWS; ++r) acc[r] = b;
  for (int cq = 0; cq < HID / 4; ++cq) {
    float w1u[4], w2u[4];
#pragma unroll
    for (int u = 0; u < 4; ++u) {
      w1u[u] = Wrel[(cq * 4 + u) * HID + f];
      w2u[u] = Wroot[(cq * 4 + u) * HID + f];
    }
#pragma unroll
    for (int r = 0; r < ROWS; ++r) {
      float4 a  = sagg4[r][cq];
      float4 xx = sx4[r][cq];
      acc[r] += a.x * w1u[0] + a.y * w1u[1] + a.z * w1u[2] + a.w * w1u[3]
              + xx.x * w2u[0] + xx.y * w2u[1] + xx.z * w2u[2] + xx.w * w2u[3];
    }
  }
  float pu[ROWS], pv[ROWS];
#pragma unroll
  for (int r = 0; r < ROWS; ++r) {
    float v = acc[r];
    v = v > 0.f ? v : 0.f;
    out[(size_t)(i0 + r) * HID + f] = v;
    pu[r] = v * wpl;
    pv[r] = v * wpr;
  }
#pragma unroll
  for (int r = 0; r < ROWS; ++r) {
#pragma unroll
    for (int o = 32; o; o >>= 1) {
      pu[r] += __shfl_down(pu[r], o);
      pv[r] += __shfl_down(pv[r], o);
    }
  }
  if ((f & 63) == 0) {
    int wd = f >> 6;
#pragma unroll
    for (int r = 0; r < ROWS; ++r) { suv[wd][0][r] = pu[r]; suv[wd][1][r] = pv[r]; }
  }
  __syncthreads();
  if (f < ROWS) uo[i0 + f] = suv[0][0][f] + suv[1][0][f];
  else if (f < 2 * ROWS) { int r = f - ROWS; vo[i0 + r] = suv[0][1][r] + suv[1][1][r]; }
}

// ---------- scalar score: score_i = tanh( sum_j u[src] + v_i + b ) ----------
template <int K>
__global__ void k_score_lite(const float* __restrict__ u, const float* __restrict__ v,
                             const int* __restrict__ src, const float* __restrict__ bprel,
                             int n, float* __restrict__ score, unsigned* __restrict__ key) {
  int i = blockIdx.x * blockDim.x + threadIdx.x;
  if (i >= n) return;
  float s = v[i] + bprel[0];
#pragma unroll
  for (int j = 0; j < K; ++j) s += u[src[i * K + j]];
  float sc = tanhf(s);
  score[i] = sc;
  unsigned bb = __float_as_uint(sc);
  key[i] = (bb & 0x80000000u) ? ~bb : (bb | 0x80000000u);
}

// ---------- single-block exact radix select (uint4-vectorized scan) ----------
__global__ void k_radix_select(const unsigned* __restrict__ key, int n, int k,
                               unsigned* __restrict__ outTG) {
  __shared__ unsigned hist[256];
  __shared__ unsigned sh_prefix, sh_remain;
  int tid = threadIdx.x, bs = blockDim.x;
  const uint4* key4 = (const uint4*)key;
  int n4 = n >> 2;
  if (tid == 0) { sh_prefix = 0u; sh_remain = (unsigned)k; }
  __syncthreads();
  for (int pass = 0; pass < 4; ++pass) {
    int shift = 24 - pass * 8;
    for (int b = tid; b < 256; b += bs) hist[b] = 0u;
    __syncthreads();
    unsigned prefix = sh_prefix;
    unsigned himask = (pass == 0) ? 0u : (0xFFFFFFFFu << (shift + 8));
    for (int i = tid; i < n4; i += bs) {
      uint4 kv = key4[i];
      unsigned a0 = kv.x, a1 = kv.y, a2 = kv.z, a3 = kv.w;
      if ((a0 & himask) == prefix) atomicAdd(&hist[(a0 >> shift) & 255u], 1u);
      if ((a1 & himask) == prefix) atomicAdd(&hist[(a1 >> shift) & 255u], 1u);
      if ((a2 & himask) == prefix) atomicAdd(&hist[(a2 >> shift) & 255u], 1u);
      if ((a3 & himask) == prefix) atomicAdd(&hist[(a3 >> shift) & 255u], 1u);
    }
    __syncthreads();
    if (tid == 0) {
      unsigned remain = sh_remain;
      int b = 255;
      for (; b > 0; --b) {
        unsigned c = hist[b];
        if (remain > c) remain -= c; else break;
      }
      sh_prefix = prefix | ((unsigned)b << shift);
      sh_remain = remain;
    }
    __syncthreads();
  }
  if (tid == 0) { outTG[0] = sh_prefix; outTG[1] = (unsigned)k - sh_remain; }
}

// ---------- compaction: strictly greater + capture boundary-equals ----------
__global__ void k_sel(const unsigned* __restrict__ key, int n,
                      const unsigned* __restrict__ TG,
                      int* __restrict__ perm, int* __restrict__ cntGt,
                      int* __restrict__ eqbuf, int* __restrict__ cntEq) {
  int i = blockIdx.x * blockDim.x + threadIdx.x;
  if (i >= n) return;
  unsigned kk = key[i], T = TG[0];
  if (kk > T) {
    perm[atomicAdd(cntGt, 1)] = i;
  } else if (kk == T) {
    int p = atomicAdd(cntEq, 1);
    if (p < MAXEQ) eqbuf[p] = i;
  }
}

// ---------- pick `need` lowest indices among boundary-equals ----------
__global__ void k_sel_eq_fin(const unsigned* __restrict__ TG, const int* __restrict__ eqbuf,
                             const int* __restrict__ cntEq, int* __restrict__ perm, int kk) {
  int lane = threadIdx.x;        // 64
  int G = (int)TG[1];
  int need = kk - G;
  int cnt = *cntEq; if (cnt > MAXEQ) cnt = MAXEQ;
  int prev = -1;
  for (int t = 0; t < need; ++t) {
    int mymin = 0x7fffffff;
    for (int u = lane; u < cnt; u += 64) {
      int v = eqbuf[u];
      if (v > prev && v < mymin) mymin = v;
    }
    for (int o = 1; o < 64; o <<= 1) mymin = min(mymin, __shfl_xor(mymin, o, 64));
    if (lane == 0) perm[G + t] = mymin;
    prev = mymin;
  }
}

// ---------- pooled gather + per-block column-max + fused grid-cell count ----------
template <int R>
__global__ __launch_bounds__(256) void k_pool_pmax(
    const float* __restrict__ x, const float* __restrict__ score,
    const int* __restrict__ perm, const float* __restrict__ pos_in,
    float* __restrict__ xout, float* __restrict__ pos_out, int store,
    float* __restrict__ pmax, int* __restrict__ counts, int G, float inv_w) {
  __shared__ float sm[2][HID];
  int f = threadIdx.x & 127;
  int half = threadIdx.x >> 7;
  int j0 = blockIdx.x * R;
  float mx = -1e30f;
  for (int r = half; r < R; r += 2) {
    int j = j0 + r;
    int node = perm[j];
    float v = score[node];
    float val = x[(size_t)node * HID + f] * v;
    if (store) xout[(size_t)j * HID + f] = val;
    mx = fmaxf(mx, val);
    if (store && f == 0) {
      float px = pos_in[node * 2], py = pos_in[node * 2 + 1];
      pos_out[j * 2] = px; pos_out[j * 2 + 1] = py;
      int cx = min(G - 1, max(0, (int)(px * inv_w)));
      int cy = min(G - 1, max(0, (int)(py * inv_w)));
      atomicAdd(&counts[cy * G + cx], 1);
    }
  }
  sm[half][f] = mx;
  __syncthreads();
  if (half == 0) pmax[blockIdx.x * HID + f] = fmaxf(sm[0][f], sm[1][f]);
}

// ---------- grid scan ----------
__global__ void k_grid_scan(const int* __restrict__ counts, int* __restrict__ starts,
                            int* __restrict__ cursor, int cells) {
  __shared__ int sums[1024];
  int t = threadIdx.x;
  int c0[4];
  int base = t * 4;
  int s = 0;
#pragma unroll
  for (int u = 0; u < 4; ++u) {
    int idx = base + u;
    c0[u] = (idx < cells) ? counts[idx] : 0;
    s += c0[u];
  }
  sums[t] = s;
  __syncthreads();
  int val = s;
  for (int off = 1; off < 1024; off <<= 1) {
    int other = (t >= off) ? sums[t - off] : 0;
    __syncthreads();
    val += other;
    sums[t] = val;
    __syncthreads();
  }
  int excl = val - s;
#pragma unroll
  for (int u = 0; u < 4; ++u) {
    int idx = base + u;
    if (idx < cells) { starts[idx] = excl; cursor[idx] = excl; excl += c0[u]; }
  }
}

__global__ void k_grid_scatter(const float2* __restrict__ pos, int m, int G, float inv_w,
                               int* __restrict__ cursor, float2* __restrict__ spos,
                               int* __restrict__ sidx) {
  int i = blockIdx.x * blockDim.x + threadIdx.x;
  if (i >= m) return;
  float2 p = pos[i];
  int cx = min(G - 1, max(0, (int)(p.x * inv_w)));
  int cy = min(G - 1, max(0, (int)(p.y * inv_w)));
  int pp = atomicAdd(&cursor[cy * G + cx], 1);
  spos[pp] = p;
  sidx[pp] = i;
}

// ---------- exact KNN, one wave per query; spans are row-contiguous after spatial sort ----------
template <int K>
__global__ __launch_bounds__(256) void k_knn_wave(const float2* __restrict__ spos,
                           const int* __restrict__ sidx,
                           const int* __restrict__ starts, const int* __restrict__ counts,
                           int m, int G, float w, float inv_w, int* __restrict__ src_out) {
  int lane = threadIdx.x & 63;
  int j = blockIdx.x * (blockDim.x >> 6) + (threadIdx.x >> 6);
  if (j >= m) return;                      // wave-uniform exit
  float2 qp = spos[j];
  int q = sidx[j];
  int cx = min(G - 1, max(0, (int)(qp.x * inv_w)));
  int cy = min(G - 1, max(0, (int)(qp.y * inv_w)));

  float bd[K]; int bi[K];
#pragma unroll
  for (int t = 0; t < K; ++t) { bd[t] = 1e30f; bi[t] = 0; }

  auto scan_span = [&](int s, int e) {
    for (int p = s + lane; p < e; p += 64) {
      if (p == j) continue;                // self (loop=False)
      float2 pp = spos[p];
      float dx = qp.x - pp.x, dy = qp.y - pp.y;
      float d = dx * dx + dy * dy;
      if (d < bd[K - 1]) {
        float dd = d; int ii = sidx[p];
#pragma unroll
        for (int t = 0; t < K; ++t) {      // branchless sorted insert, static idx
          bool sw = dd < bd[t];
          float od = bd[t]; int oi = bi[t];
          if (sw) { bd[t] = dd; bi[t] = ii; dd = od; ii = oi; }
        }
      }
    }
  };

  {
    int xl = max(0, cx - 1), xh = min(G - 1, cx + 1);
    int y0 = max(0, cy - 1), y1 = min(G - 1, cy + 1);
    int ss[3], ee[3]; int nr = 0;
    for (int y = y0; y <= y1; ++y) {
      int b = y * G;
      ss[nr] = starts[b + xl];
      ee[nr] = starts[b + xh] + counts[b + xh];
      ++nr;
    }
    for (int t = 0; t < nr; ++t) scan_span(ss[t], ee[t]);
  }

  int r = 1;
  unsigned long long mg[K];
  while (true) {
    unsigned long long tmp[K];
#pragma unroll
    for (int t = 0; t < K; ++t)
      tmp[t] = ((unsigned long long)__float_as_uint(bd[t]) << 32) | (unsigned)bi[t];
#pragma unroll
    for (int t = 0; t < K; ++t) {
      unsigned long long mn = tmp[0];
#pragma unroll
      for (int o = 1; o < 64; o <<= 1) {
        unsigned long long ot = __shfl_xor(mn, o, 64);
        if (ot < mn) mn = ot;
      }
      mg[t] = mn;
      if (tmp[0] == mn) {
#pragma unroll
        for (int s2 = 0; s2 < K - 1; ++s2) tmp[s2] = tmp[s2 + 1];
        tmp[K - 1] = ~0ull;
      }
    }
    float kth = __uint_as_float((unsigned)(mg[K - 1] >> 32));
    float bnd = 1e30f;
    if (cx - r > 0)     bnd = fminf(bnd, qp.x - (float)(cx - r) * w);
    if (cx + r < G - 1) bnd = fminf(bnd, (float)(cx + r + 1) * w - qp.x);
    if (cy - r > 0)     bnd = fminf(bnd, qp.y - (float)(cy - r) * w);
    if (cy + r < G - 1) bnd = fminf(bnd, (float)(cy + r + 1) * w - qp.y);
    if (bnd > 1e29f) break;                // grid exhausted
    float bb = fmaxf(bnd, 0.f) * 0.999f;
    if (kth < bb * bb) break;
    ++r;
    int xl = max(0, cx - r), xh = min(G - 1, cx + r);
    int yt = cy - r, yb = cy + r;
    if (yt >= 0)     { int b = yt * G; scan_span(starts[b + xl], starts[b + xh] + counts[b + xh]); }
    if (yb <= G - 1) { int b = yb * G; scan_span(starts[b + xl], starts[b + xh] + counts[b + xh]); }
    int ylo = max(0, cy - r + 1), yhi = min(G - 1, cy + r - 1);
    for (int y = ylo; y <= yhi; ++y) {
      int b = y * G;
      if (cx - r >= 0)     { int c = b + cx - r; scan_span(starts[c], starts[c] + counts[c]); }
      if (cx + r <= G - 1) { int c = b + cx + r; scan_span(starts[c], starts[c] + counts[c]); }
    }
  }
  if (lane == 0) {
#pragma unroll
    for (int t = 0; t < K; ++t) src_out[q * K + t] = (int)(unsigned)(mg[t] & 0xffffffffu);
  }
}

// ---------- final: reduce pmax segments -> xs, then MLP head ----------
__global__ __launch_bounds__(1024) void k_final(const float* __restrict__ pmax,
                        int P0, int P1, int P2,
                        const float* __restrict__ W1, const float* __restrict__ b1,
                        const float* __restrict__ W2, const float* __restrict__ b2,
                        float* __restrict__ out) {
  __shared__ float red[8][HID];
  __shared__ float sxs[3 * HID];
  __shared__ float h1[HID];
  int f = threadIdx.x & 127, ch = threadIdx.x >> 7;   // 1024 threads
  int off0 = 0, off1 = P0, off2 = P0 + P1, off3 = P0 + P1 + P2;
  int lo[3] = {off0, off1, off2};
  int hi[3] = {off1, off2, off3};
  for (int l = 0; l < 3; ++l) {
    float mx = -1e30f;
    for (int p = lo[l] + ch; p < hi[l]; p += 8) mx = fmaxf(mx, pmax[p * HID + f]);
    red[ch][f] = mx;
    __syncthreads();
    if (ch == 0) {
      float m2 = red[0][f];
#pragma unroll
      for (int u = 1; u < 8; ++u) m2 = fmaxf(m2, red[u][f]);
      sxs[l * HID + f] = m2;
    }
    __syncthreads();
  }
  if (threadIdx.x < HID) {
    float acc = b1[f];
    for (int c = 0; c < 3 * HID; ++c) acc += sxs[c] * W1[c * HID + f];
    h1[f] = acc > 0.f ? acc : 0.f;
  }
  __syncthreads();
  if (threadIdx.x < 5) {
    float a = b2[threadIdx.x];
    for (int c = 0; c < HID; ++c) a += h1[c] * W2[c * 5 + threadIdx.x];
    out[threadIdx.x] = a;
  }
}

extern "C" void kernel_launch(void* const* d_in, const int* in_sizes, int n_in,
                              void* d_out, int out_size, void* d_ws, size_t ws_size,
                              hipStream_t stream) {
  const float* x_in   = (const float*)d_in[0];
  const float* pos_in = (const float*)d_in[1];
  const int*   ei     = (const int*)d_in[2];
  const float* Wrel   = (const float*)d_in[3];
  const float* brel   = (const float*)d_in[4];
  const float* Wroot  = (const float*)d_in[5];
  const float* Wprel  = (const float*)d_in[6];
  const float* bprel  = (const float*)d_in[7];
  const float* Wproot = (const float*)d_in[8];
  const float* W1     = (const float*)d_in[9];
  const float* b1     = (const float*)d_in[10];
  const float* W2     = (const float*)d_in[11];
  const float* b2     = (const float*)d_in[12];
  float* out = (float*)d_out;

  const int N0 = in_sizes[0] / HID;   // 20000
  const int P0 = (N0 / 2) / PR, P1 = (N0 / 4) / PR, P2 = (N0 / 8) / PR;  // 500/250/125

  // workspace layout (16B-aligned regions)
  char* w = (char*)d_ws;
  float*    xB     = (float*)w;    w += (size_t)N0 * HID * 4;
  float*    xA     = (float*)w;    w += (size_t)(N0 / 2) * HID * 4;
  float*    score  = (float*)w;    w += (size_t)N0 * 4;
  unsigned* key    = (unsigned*)w; w += (size_t)N0 * 4;
  float*    ubuf   = (float*)w;    w += (size_t)N0 * 4;
  float*    vbuf   = (float*)w;    w += (size_t)N0 * 4;
  float*    posA   = (float*)w;    w += (size_t)(N0 / 2) * 2 * 4;
  float*    posB   = (float*)w;    w += (size_t)(N0 / 2) * 2 * 4;
  int*      srcbuf = (int*)w;      w += (size_t)(N0 / 2) * 8 * 4;
  int*      permb  = (int*)w;      w += (size_t)(N0 / 2) * 4;
  float*    pmax   = (float*)w;    w += (size_t)(P0 + P1 + P2) * HID * 4;
  unsigned* TG     = (unsigned*)w; w += 16;
  int*      cnt    = (int*)w;      w += 32;                 // cntGt[3], cntEq[3]
  int*      eqbuf  = (int*)w;      w += MAXEQ * 4;
  int*      counts = (int*)w;      w += 4096 * 4;
  int*      starts = (int*)w;      w += 4096 * 4;
  int*      cursor = (int*)w;      w += 4096 * 4;
  float2*   spos   = (float2*)w;   w += (size_t)(N0 / 2) * 8;
  int*      sidx   = (int*)w;      w += (size_t)(N0 / 2) * 4;
  (void)ws_size; (void)n_in; (void)out_size;

  hipMemsetAsync(cnt, 0, 32, stream);

  int n = N0;
  const float* xcur   = x_in;
  const float* poscur = pos_in;
  const int*   srccur = ei;
  int kcur = 6;                 // E0/N0 == 6 (K0)
  int Poff = 0;

  for (int l = 0; l < 3; ++l) {
    const int kk = n / 2;
    int G = (int)ceilf(sqrtf((float)kk / 2.5f));
    if (G > 64) G = 64;
    if (G < 1) G = 1;
    int cells = G * G;
    float cw = 100.f / (float)G;
    float inv_w = (float)G / 100.f;

    if (kcur == 6) {
      k_conv_fused<8, 6><<<n / 8, HID, 0, stream>>>(xcur, srccur, 1.f / 6.f,
          Wrel + l * HID * HID, Wroot + l * HID * HID, brel + l * HID,
          Wprel + l * HID, Wproot + l * HID, xB, ubuf, vbuf);
      k_score_lite<6><<<(n + 255) / 256, 256, 0, stream>>>(ubuf, vbuf, srccur, bprel + l,
                                                           n, score, key);
    } else {
      k_conv_fused<8, 8><<<n / 8, HID, 0, stream>>>(xcur, srccur, 1.f / 8.f,
          Wrel + l * HID * HID, Wroot + l * HID * HID, brel + l * HID,
          Wprel + l * HID, Wproot + l * HID, xB, ubuf, vbuf);
      k_score_lite<8><<<(n + 255) / 256, 256, 0, stream>>>(ubuf, vbuf, srccur, bprel + l,
                                                           n, score, key);
    }
    k_radix_select<<<1, 1024, 0, stream>>>(key, n, kk, TG);
    k_sel<<<(n + 255) / 256, 256, 0, stream>>>(key, n, TG, permb, cnt + l, eqbuf, cnt + 3 + l);
    k_sel_eq_fin<<<1, 64, 0, stream>>>(TG, eqbuf, cnt + 3 + l, permb, kk);

    float* pos_out = (l == 0) ? posA : posB;
    int store = (l < 2) ? 1 : 0;
    if (store) hipMemsetAsync(counts, 0, (size_t)cells * 4, stream);
    k_pool_pmax<PR><<<kk / PR, 256, 0, stream>>>(xB, score, permb, poscur, xA, pos_out,
                                                 store, pmax + (size_t)Poff * HID,
                                                 counts, G, inv_w);
    Poff += kk / PR;
    n = kk;
    if (l < 2) {
      k_grid_scan<<<1, 1024, 0, stream>>>(counts, starts, cursor, cells);
      k_grid_scatter<<<(n + 255) / 256, 256, 0, stream>>>((const float2*)pos_out, n, G, inv_w,
                                                          cursor, spos, sidx);
      if (l == 0) { k_knn_wave<6><<<(n + 3) / 4, 256, 0, stream>>>(spos, sidx, starts, counts,
                                                                   n, G, cw, inv_w, srcbuf); kcur = 6; }
      else        { k_knn_wave<8><<<(n + 3) / 4, 256, 0, stream>>>(spos, sidx, starts, counts,
                                                                   n, G, cw, inv_w, srcbuf); kcur = 8; }
    }
    xcur = xA; poscur = pos_out; srccur = srcbuf;
  }
  k_final<<<1, 1024, 0, stream>>>(pmax, P0, P1, P2, W1, b1, W2, b2, out);
}